// Round 9
// baseline (12517.966 us; speedup 1.0000x reference)
//
#include <hip/hip_runtime.h>
#include <hip/hip_bf16.h>

#define B_ 16
#define T_ 12
#define N_ 2000
#define E_ 8000
#define M_ 32000                 // B_*N_
#define ETOT (B_*E_ + M_)        // 160000 edges incl. self loops
#define D_ 64
#define TB_ 4                    // timesteps batched per GAT launch

typedef __hip_bfloat16 bf16;
typedef unsigned short u16;

__device__ __forceinline__ float bfu(u16 u){ return __uint_as_float(((unsigned int)u)<<16); }
__device__ __forceinline__ u16 f2bu(float f){
  unsigned int x = __float_as_uint(f);
  x += 0x7FFFu + ((x >> 16) & 1u);
  return (u16)(x >> 16);
}
__device__ __forceinline__ float wred64(float x){
  x += __shfl_xor(x,1); x += __shfl_xor(x,2); x += __shfl_xor(x,4);
  x += __shfl_xor(x,8); x += __shfl_xor(x,16); x += __shfl_xor(x,32);
  return x;
}

// ---------------- weight prep (all bf16, packed for coalesced ushort4 loads) ----
// wqP u16 [L][16][3][64][4]: bf16(Wqkv[l][s*64+j][d4*4+u])           24576
// woP u16 [L][16][64][4]   : bf16(Wo[l][j*64 + d4*4+u])               8192
// w1P u16 [L][16][2][64][4]: bf16(Wf1[l][s*64+j][d4*4+u])            32768
// w2P u16 [L][32][64][4]   : bf16(Wf2[l][j*128 + hc4*4+u])           16384
__global__ void k_prep(const float* __restrict__ Wqkv, const float* __restrict__ Wo,
                       const float* __restrict__ Wf1, const float* __restrict__ Wf2,
                       u16* __restrict__ wqP, u16* __restrict__ woP,
                       u16* __restrict__ w1P, u16* __restrict__ w2P){
  int i = blockIdx.x*256 + threadIdx.x;    // 320 blocks -> 81920 threads exactly
  if(i < 24576){
    int l=i/12288, r0=i-l*12288;
    int d4=r0/768, r1=r0-d4*768;
    int s=r1/256, r2=r1-s*256;
    int jj=r2>>2, u=r2&3;
    wqP[i] = f2bu(Wqkv[l*12288 + (s*64+jj)*64 + d4*4+u]);
  } else if(i < 32768){
    int k2=i-24576;
    int l=k2/4096, r0=k2-l*4096;
    int d4=r0/256, r1=r0-d4*256, jj=r1>>2, u=r1&3;
    woP[k2] = f2bu(Wo[l*4096 + jj*64 + d4*4+u]);
  } else if(i < 65536){
    int k2=i-32768;                       // [0, 32768)
    int l=k2>>14, r0=k2&16383;
    int d4=r0>>9, r1=r0&511;
    int s=r1>>8, r2=r1&255;
    int jj=r2>>2, u=r2&3;
    w1P[k2] = f2bu(Wf1[l*8192 + (s*64+jj)*64 + d4*4+u]);
  } else {
    int k2=i-65536;                       // [0, 16384)
    int l=k2>>13, r0=k2&8191;
    int hc4=r0>>8, r1=r0&255;
    int jj=r1>>2, u=r1&3;
    w2P[k2] = f2bu(Wf2[l*8192 + jj*128 + hc4*4+u]);
  }
}

// ---------------- CSR build ----------------
__global__ void k_zero(int* __restrict__ p, int n){
  int i = blockIdx.x*256 + threadIdx.x; if(i<n) p[i]=0;
}

__global__ void k_hist(const int* __restrict__ ei, int* __restrict__ deg){
  int e = blockIdx.x*256 + threadIdx.x; if(e>=ETOT) return;
  int dst;
  if (e < B_*E_){ int b = e / E_; int k = e - b*E_; dst = ei[E_ + k] + b*N_; }
  else dst = e - B_*E_;
  atomicAdd(&deg[dst], 1);
}

__global__ void k_scan1(const int* __restrict__ deg, int* __restrict__ offs, int* __restrict__ bsums){
  __shared__ int s[256];
  int tid = threadIdx.x; int g = blockIdx.x*256 + tid;
  s[tid] = deg[g]; __syncthreads();
  for(int off=1; off<256; off<<=1){
    int a = (tid>=off) ? s[tid-off] : 0; __syncthreads();
    s[tid] += a; __syncthreads();
  }
  offs[g+1] = s[tid];
  if(tid==255) bsums[blockIdx.x] = s[255];
}

__global__ void k_scan2(const int* __restrict__ bsums, int* __restrict__ boffs){
  __shared__ int s[128];
  int tid = threadIdx.x;
  int v = (tid<125) ? bsums[tid] : 0;
  s[tid] = v; __syncthreads();
  for(int off=1; off<128; off<<=1){
    int a = (tid>=off) ? s[tid-off] : 0; __syncthreads();
    s[tid] += a; __syncthreads();
  }
  if(tid<125) boffs[tid] = s[tid] - v;
}

__global__ void k_scan3(int* __restrict__ offs, const int* __restrict__ boffs){
  int tid = threadIdx.x; int g = blockIdx.x*256 + tid;
  offs[g+1] += boffs[blockIdx.x];
  if(g==0) offs[0]=0;
}

__global__ void k_scatter(const int* __restrict__ ei, const int* __restrict__ offs,
                          int* __restrict__ cursor, int* __restrict__ csr){
  int e = blockIdx.x*256 + threadIdx.x; if(e>=ETOT) return;
  int src, dst;
  if (e < B_*E_){ int b=e/E_; int k=e-b*E_; src=ei[k]+b*N_; dst=ei[E_+k]+b*N_; }
  else { src = e - B_*E_; dst = src; }
  int pos = atomicAdd(&cursor[dst], 1);
  csr[offs[dst]+pos] = src;
}

// ---------------- fused GAT1 + GAT2 feature/score, batched over TB_ timesteps ----
__global__ __launch_bounds__(256) void k_gat12(
  const float* __restrict__ x_seq, const float* __restrict__ W1,
  const float* __restrict__ as1, const float* __restrict__ ad1, const float* __restrict__ b1,
  const float* __restrict__ W2, const float* __restrict__ as2, const float* __restrict__ ad2,
  const int* __restrict__ offs, const int* __restrict__ csr,
  u16* __restrict__ h2u, float* __restrict__ asc, float* __restrict__ adc, int t0)
{
  __shared__ float W2s[2048];       // [k=32][c=64] fp32
  __shared__ float a2s[64], a2d[64];
  int tid = threadIdx.x;
  for(int i=tid;i<2048;i+=256) W2s[i]=W2[i];
  if(tid<64){ a2s[tid]=as2[tid]; a2d[tid]=ad2[tid]; }
  __syncthreads();

  int tb = blockIdx.y, t = t0 + tb;
  int id = blockIdx.x*256 + tid;     // 500*256 = M_*4
  int m = id>>2, q = id&3;

  float sS[4], sD[4];
  #pragma unroll
  for(int h=0;h<4;h++){
    float a=0.f, d=0.f;
    #pragma unroll
    for(int c=0;c<8;c++){ float w=W1[h*8+c]; a+=w*as1[h*8+c]; d+=w*ad1[h*8+c]; }
    sS[h]=a; sD[h]=d;
  }
  unsigned um=(unsigned)m, b=um/N_, n=um-b*N_;
  const float* xsl = x_seq + (size_t)(b*T_+t)*N_;
  float xm = xsl[n];
  int e0=offs[m], e1=offs[m+1];
  // single-pass softmax (scores are O(1): no overflow risk)
  float sum[4]={0,0,0,0}, ax[4]={0,0,0,0};
  for(int e=e0;e<e1;e++){
    unsigned s=(unsigned)csr[e]; unsigned sn=s - (s/N_)*N_;
    float xv = xsl[sn];
    #pragma unroll
    for(int h=0;h<4;h++){
      float ee = xv*sS[h] + xm*sD[h]; ee = ee>0.f ? ee : 0.2f*ee;
      float w = __expf(ee); sum[h]+=w; ax[h]+=w*xv;
    }
  }
  float A[4];
  #pragma unroll
  for(int h=0;h<4;h++) A[h] = ax[h]/(sum[h]+1e-16f);

  float acc[16];
  #pragma unroll
  for(int c=0;c<16;c++) acc[c]=0.f;
  #pragma unroll
  for(int k=0;k<32;k++){
    int h = k>>3;
    float v = A[h]*W1[k] + b1[k]; v = v>0.f ? v : 0.f;   // relu(out1)
    #pragma unroll
    for(int c=0;c<16;c++) acc[c] += v*W2s[k*64 + q*16 + c];
  }
  // pack bf16, 4x uint2 stores
  uint2* hp = (uint2*)(h2u + ((size_t)tb*M_ + m)*64 + q*16);
  #pragma unroll
  for(int c2=0;c2<4;c2++){
    uint2 p;
    p.x = (unsigned)f2bu(acc[4*c2+0]) | ((unsigned)f2bu(acc[4*c2+1])<<16);
    p.y = (unsigned)f2bu(acc[4*c2+2]) | ((unsigned)f2bu(acc[4*c2+3])<<16);
    hp[c2] = p;
  }
  float ss=0.f, sd=0.f;
  #pragma unroll
  for(int c=0;c<16;c++){ ss += acc[c]*a2s[q*16+c]; sd += acc[c]*a2d[q*16+c]; }
  asc[((size_t)tb*M_+m)*4+q]=ss; adc[((size_t)tb*M_+m)*4+q]=sd;
}

// ---------------- GAT2 softmax-aggregate + bias + relu + PE, batched ----------------
__global__ __launch_bounds__(256) void k_gat2b(
  const u16* __restrict__ h2u, const float* __restrict__ asc, const float* __restrict__ adc,
  const float* __restrict__ b2, const int* __restrict__ offs, const int* __restrict__ csr,
  float* __restrict__ seq, int t0)
{
  int tb = blockIdx.y, t = t0 + tb;
  int id = blockIdx.x*256 + threadIdx.x;
  int m = id>>2, h = id&3;
  float am = adc[((size_t)tb*M_+m)*4+h];
  int e0=offs[m], e1=offs[m+1];
  float sum=0.f;
  float A[16];
  #pragma unroll
  for(int c=0;c<16;c++) A[c]=0.f;
  for(int e=e0;e<e1;e++){
    int s=csr[e];
    float ee = asc[((size_t)tb*M_+s)*4+h] + am; ee = ee>0.f ? ee : 0.2f*ee;
    float w = __expf(ee); sum += w;
    const uint2* hp = (const uint2*)(h2u + ((size_t)tb*M_ + s)*64 + h*16);
    #pragma unroll
    for(int c2=0;c2<4;c2++){
      uint2 p = hp[c2];
      A[4*c2+0] += w*bfu((u16)(p.x));
      A[4*c2+1] += w*bfu((u16)(p.x>>16));
      A[4*c2+2] += w*bfu((u16)(p.y));
      A[4*c2+3] += w*bfu((u16)(p.y>>16));
    }
  }
  float inv = 1.f/(sum + 1e-16f);
  #pragma unroll
  for(int c=0;c<16;c++){
    int ch = h*16 + c;
    float v = A[c]*inv + b2[ch]; v = v>0.f ? v : 0.f;
    float ang = (float)t * __expf(-0.14391156463f * (float)(ch & ~1));  // ln(1e4)/64
    float pe = (ch&1) ? __cosf(ang) : __sinf(ang);
    seq[((size_t)t*M_ + m)*64 + ch] = v + pe;
  }
}

// ---------------- fused transformer layer: qkv + attn + Wo + LN1 + FF + LN2 -------
// Per-wave LDS union U[w][2448]:
//   phase 1: [0..767] = X[12][64]
//   phase 2: [s*816 + t*68 + c] = Q/K/V (pad 68), Q region overwritten by O
//   phase 3: Q region overwritten by LN1 output y[12][64]
//   FF:      [816 + t*128 + hc] = hidden h[12][128] (K/V region, dead)
// FF phases are wave-private (no __syncthreads; DS ops are wave-ordered).
__global__ __launch_bounds__(256) void k_layer(
  float* __restrict__ seq,
  const u16* __restrict__ wqP,   // [16][3][64][4] packed bf16
  const u16* __restrict__ woP,   // [16][64][4]    packed bf16
  const u16* __restrict__ w1P,   // [16][2][64][4] packed bf16
  const u16* __restrict__ w2P,   // [32][64][4]    packed bf16
  const float* __restrict__ bqkv, const float* __restrict__ bo,
  const float* __restrict__ bf1,  const float* __restrict__ bf2,
  const float* __restrict__ g1,   const float* __restrict__ be1,
  const float* __restrict__ g2,   const float* __restrict__ be2,
  int last)
{
  __shared__ __align__(16) float U[4][2448];   // 39168 B total
  int tid = threadIdx.x, w = tid>>6, j = tid&63;
  int m = blockIdx.x*4 + w;
  float* Uw = U[w];

  float xr[12];
  #pragma unroll
  for(int t=0;t<12;t++){ float x = seq[((size_t)t*M_ + m)*64 + j]; xr[t]=x; Uw[t*64+j]=x; }
  float bqj = bqkv[j], bkj = bqkv[64+j], bvj = bqkv[128+j];
  float boj = bo[j], gj = g1[j], bej = be1[j];
  float b1a = bf1[j], b1b = bf1[64+j];
  float b2j = bf2[j], g2j = g2[j], be2j = be2[j];
  __syncthreads();

  // phase 1: qkv projection. lane j owns column j of q,k,v for all t.
  float q[12],k[12],v[12];
  #pragma unroll
  for(int t=0;t<12;t++){ q[t]=bqj; k[t]=bkj; v[t]=bvj; }
  const ushort4* wq4 = (const ushort4*)wqP;
  #pragma unroll
  for(int d4=0; d4<16; d4++){
    float4 xv[12];
    #pragma unroll
    for(int t=0;t<12;t++) xv[t] = *(const float4*)&Uw[t*64 + d4*4];
    ushort4 aq = wq4[(d4*3+0)*64 + j];
    ushort4 ak = wq4[(d4*3+1)*64 + j];
    ushort4 av = wq4[(d4*3+2)*64 + j];
    float q0=bfu(aq.x),q1=bfu(aq.y),q2=bfu(aq.z),q3=bfu(aq.w);
    float k0=bfu(ak.x),k1=bfu(ak.y),k2=bfu(ak.z),k3=bfu(ak.w);
    float v0=bfu(av.x),v1=bfu(av.y),v2=bfu(av.z),v3=bfu(av.w);
    #pragma unroll
    for(int t=0;t<12;t++){
      q[t]+=xv[t].x*q0; q[t]+=xv[t].y*q1; q[t]+=xv[t].z*q2; q[t]+=xv[t].w*q3;
      k[t]+=xv[t].x*k0; k[t]+=xv[t].y*k1; k[t]+=xv[t].z*k2; k[t]+=xv[t].w*k3;
      v[t]+=xv[t].x*v0; v[t]+=xv[t].y*v1; v[t]+=xv[t].z*v2; v[t]+=xv[t].w*v3;
    }
  }
  #pragma unroll
  for(int t=0;t<12;t++){
    Uw[       t*68 + j]=q[t];
    Uw[ 816 + t*68 + j]=k[t];
    Uw[1632 + t*68 + j]=v[t];
  }
  __syncthreads();

  // phase 2: attention. 48 lanes own (head h, time t); in-register softmax.
  if(j < 48){
    int h = j/12, t = j - h*12;
    float* qrow = &Uw[t*68 + h*16];
    float4 a0=((float4*)qrow)[0], a1=((float4*)qrow)[1], a2=((float4*)qrow)[2], a3=((float4*)qrow)[3];
    float s[12];
    #pragma unroll
    for(int t2=0;t2<12;t2++){
      const float4* kr = (const float4*)&Uw[816 + t2*68 + h*16];
      float4 c0=kr[0], c1=kr[1], c2=kr[2], c3=kr[3];
      float d = a0.x*c0.x + a0.y*c0.y + a0.z*c0.z + a0.w*c0.w
              + a1.x*c1.x + a1.y*c1.y + a1.z*c1.z + a1.w*c1.w
              + a2.x*c2.x + a2.y*c2.y + a2.z*c2.z + a2.w*c2.w
              + a3.x*c3.x + a3.y*c3.y + a3.z*c3.z + a3.w*c3.w;
      s[t2] = d*0.25f;                 // 1/sqrt(16)
    }
    float mx = s[0];
    #pragma unroll
    for(int t2=1;t2<12;t2++) mx = fmaxf(mx, s[t2]);
    float sum = 0.f;
    #pragma unroll
    for(int t2=0;t2<12;t2++){ s[t2]=__expf(s[t2]-mx); sum+=s[t2]; }
    float inv = 1.f/sum;
    float4 o0=make_float4(0,0,0,0), o1=o0, o2=o0, o3=o0;
    #pragma unroll
    for(int t2=0;t2<12;t2++){
      const float4* vr = (const float4*)&Uw[1632 + t2*68 + h*16];
      float4 c0=vr[0], c1=vr[1], c2=vr[2], c3=vr[3];
      float ww = s[t2];
      o0.x+=ww*c0.x; o0.y+=ww*c0.y; o0.z+=ww*c0.z; o0.w+=ww*c0.w;
      o1.x+=ww*c1.x; o1.y+=ww*c1.y; o1.z+=ww*c1.z; o1.w+=ww*c1.w;
      o2.x+=ww*c2.x; o2.y+=ww*c2.y; o2.z+=ww*c2.z; o2.w+=ww*c2.w;
      o3.x+=ww*c3.x; o3.y+=ww*c3.y; o3.z+=ww*c3.z; o3.w+=ww*c3.w;
    }
    o0.x*=inv;o0.y*=inv;o0.z*=inv;o0.w*=inv;
    o1.x*=inv;o1.y*=inv;o1.z*=inv;o1.w*=inv;
    o2.x*=inv;o2.y*=inv;o2.z*=inv;o2.w*=inv;
    o3.x*=inv;o3.y*=inv;o3.z*=inv;o3.w*=inv;
    ((float4*)qrow)[0]=o0; ((float4*)qrow)[1]=o1; ((float4*)qrow)[2]=o2; ((float4*)qrow)[3]=o3;
  }
  __syncthreads();

  // phase 3: Wo + residual + LN1. O in Q region; y overwrites it (all O reads first).
  float acc[12];
  #pragma unroll
  for(int t=0;t<12;t++) acc[t]=boj;
  const ushort4* wo4 = (const ushort4*)woP;
  #pragma unroll
  for(int d4=0; d4<16; d4++){
    ushort4 aw = wo4[d4*64 + j];
    float w0=bfu(aw.x), w1=bfu(aw.y), w2=bfu(aw.z), w3=bfu(aw.w);
    #pragma unroll
    for(int t=0;t<12;t++){
      float4 ov = *(const float4*)&Uw[t*68 + d4*4];
      acc[t]+=ov.x*w0; acc[t]+=ov.y*w1; acc[t]+=ov.z*w2; acc[t]+=ov.w*w3;
    }
  }
  float y[12];
  #pragma unroll
  for(int t=0;t<12;t++){
    float x = xr[t] + acc[t];
    float mu = wred64(x)*(1.f/64.f);
    float dd = x - mu;
    float var = wred64(dd*dd)*(1.f/64.f);
    y[t] = dd*rsqrtf(var+1e-5f)*gj + bej;
    Uw[t*68 + j] = y[t];              // wave-private; DS ops wave-ordered
  }

  // FF1: lane j owns hidden units j and 64+j; x broadcast from Uw.
  float h0[12], h1[12];
  #pragma unroll
  for(int t=0;t<12;t++){ h0[t]=b1a; h1[t]=b1b; }
  const ushort4* w14 = (const ushort4*)w1P;
  #pragma unroll
  for(int d4=0; d4<16; d4++){
    ushort4 wa = w14[(d4*2+0)*64 + j];
    ushort4 wb = w14[(d4*2+1)*64 + j];
    float a0=bfu(wa.x),a1=bfu(wa.y),a2=bfu(wa.z),a3=bfu(wa.w);
    float c0=bfu(wb.x),c1=bfu(wb.y),c2=bfu(wb.z),c3=bfu(wb.w);
    #pragma unroll
    for(int t=0;t<12;t++){
      float4 xv = *(const float4*)&Uw[t*68 + d4*4];
      h0[t] += xv.x*a0 + xv.y*a1 + xv.z*a2 + xv.w*a3;
      h1[t] += xv.x*c0 + xv.y*c1 + xv.z*c2 + xv.w*c3;
    }
  }
  #pragma unroll
  for(int t=0;t<12;t++){
    Uw[816 + t*128 + j]      = fmaxf(h0[t], 0.f);
    Uw[816 + t*128 + 64 + j] = fmaxf(h1[t], 0.f);
  }

  // FF2: lane j owns output column j; h broadcast from Uw.
  float y2[12];
  #pragma unroll
  for(int t=0;t<12;t++) y2[t]=b2j;
  const ushort4* w24 = (const ushort4*)w2P;
  #pragma unroll
  for(int hc4=0; hc4<32; hc4++){
    ushort4 wc = w24[hc4*64 + j];
    float c0=bfu(wc.x),c1=bfu(wc.y),c2=bfu(wc.z),c3=bfu(wc.w);
    #pragma unroll
    for(int t=0;t<12;t++){
      float4 hv = *(const float4*)&Uw[816 + t*128 + hc4*4];
      y2[t] += hv.x*c0 + hv.y*c1 + hv.z*c2 + hv.w*c3;
    }
  }

  // residual + LN2 + store (last layer: only t=11 needed by k_head)
  #pragma unroll
  for(int t=0;t<12;t++){
    float x = y[t] + y2[t];
    float mu = wred64(x)*(1.f/64.f);
    float dd = x - mu;
    float var = wred64(dd*dd)*(1.f/64.f);
    float out = dd*rsqrtf(var+1e-5f)*g2j + be2j;
    if(!last || t==11)
      seq[((size_t)t*M_ + m)*64 + j] = out;
  }
}

// ---------------- prediction head ----------------
__global__ void k_head(const float* __restrict__ seq, const float* __restrict__ Wh,
                       const float* __restrict__ bh, float* __restrict__ out){
  int m = blockIdx.x*256 + threadIdx.x; if(m>=M_) return;
  const float* row = seq + ((size_t)11*M_ + m)*64;
  float a0=bh[0], a1=bh[1], a2=bh[2];
  #pragma unroll
  for(int d=0;d<64;d++){
    float x = row[d];
    a0 += x*Wh[d]; a1 += x*Wh[64+d]; a2 += x*Wh[128+d];
  }
  unsigned b=(unsigned)m/N_, n=(unsigned)m-b*N_;
  out[(b*3+0)*N_+n] = a0;
  out[(b*3+1)*N_+n] = a1;
  out[(b*3+2)*N_+n] = a2;
}

extern "C" void kernel_launch(void* const* d_in, const int* in_sizes, int n_in,
                              void* d_out, int out_size, void* d_ws, size_t ws_size,
                              hipStream_t stream)
{
  const float* x_seq=(const float*)d_in[0];
  const int*   ei   =(const int*)d_in[1];
  const float* W1   =(const float*)d_in[2];
  const float* as1  =(const float*)d_in[3];
  const float* ad1  =(const float*)d_in[4];
  const float* b1   =(const float*)d_in[5];
  const float* W2   =(const float*)d_in[6];
  const float* as2  =(const float*)d_in[7];
  const float* ad2  =(const float*)d_in[8];
  const float* b2   =(const float*)d_in[9];
  const float* Wqkv =(const float*)d_in[10];
  const float* bqkv =(const float*)d_in[11];
  const float* Wo   =(const float*)d_in[12];
  const float* bo   =(const float*)d_in[13];
  const float* Wf1  =(const float*)d_in[14];
  const float* bf1p =(const float*)d_in[15];
  const float* Wf2  =(const float*)d_in[16];
  const float* bf2p =(const float*)d_in[17];
  const float* g1   =(const float*)d_in[18];
  const float* be1  =(const float*)d_in[19];
  const float* g2   =(const float*)d_in[20];
  const float* be2  =(const float*)d_in[21];
  const float* Wh   =(const float*)d_in[22];
  const float* bh   =(const float*)d_in[23];

  // workspace layout (~116 MB)
  float* seq  = (float*)d_ws;            // [T][M][64]    24,576,000 f
  float* asc  = seq  + 24576000;         // [TB_][M][4]      512,000 f
  float* adc  = asc  + 512000;           //                  512,000 f
  int* deg    = (int*)(adc + 512000);
  int* cursor = deg + M_;
  int* offs   = cursor + M_;             // M_+1 used
  int* bsums  = offs + (M_ + 2);
  int* boffs  = bsums + 128;
  int* csr    = boffs + 128;             // ETOT
  u16* h2u    = (u16*)(csr + ETOT);      // [TB_][M][64]  8,192,000 u16
  u16* wqP    = h2u + (size_t)TB_*M_*64; // 24576
  u16* woP    = wqP + 24576;             // 8192
  u16* w1P    = woP + 8192;              // 32768
  u16* w2P    = w1P + 32768;             // 16384

  k_prep   <<<dim3(320), dim3(256), 0, stream>>>(Wqkv, Wo, Wf1, Wf2, wqP, woP, w1P, w2P);

  // CSR build (edge list identical for all t)
  k_zero   <<<dim3((2*M_+255)/256), dim3(256), 0, stream>>>(deg, 2*M_);
  k_hist   <<<dim3((ETOT+255)/256), dim3(256), 0, stream>>>(ei, deg);
  k_scan1  <<<dim3(125), dim3(256), 0, stream>>>(deg, offs, bsums);
  k_scan2  <<<dim3(1),   dim3(128), 0, stream>>>(bsums, boffs);
  k_scan3  <<<dim3(125), dim3(256), 0, stream>>>(offs, boffs);
  k_scatter<<<dim3((ETOT+255)/256), dim3(256), 0, stream>>>(ei, offs, cursor, csr);

  for(int t0=0; t0<T_; t0+=TB_){
    k_gat12<<<dim3(500,TB_), dim3(256), 0, stream>>>(x_seq, W1, as1, ad1, b1,
                                                     W2, as2, ad2, offs, csr, h2u, asc, adc, t0);
    k_gat2b<<<dim3(500,TB_), dim3(256), 0, stream>>>(h2u, asc, adc, b2, offs, csr, seq, t0);
  }

  for(int i=0;i<2;i++){
    k_layer<<<dim3(8000), dim3(256), 0, stream>>>(seq,
        wqP + (size_t)i*12288, woP + (size_t)i*4096,
        w1P + (size_t)i*16384, w2P + (size_t)i*8192,
        bqkv + (size_t)i*192,  bo   + (size_t)i*64,
        bf1p + (size_t)i*128,  bf2p + (size_t)i*64,
        g1   + (size_t)i*64,   be1  + (size_t)i*64,
        g2   + (size_t)i*64,   be2  + (size_t)i*64,
        i==1);
  }

  k_head<<<dim3(125), dim3(256), 0, stream>>>(seq, Wh, bh, (float*)d_out);
}

// Round 10
// 1382.548 us; speedup vs baseline: 9.0543x; 9.0543x over previous
//
#include <hip/hip_runtime.h>
#include <hip/hip_bf16.h>

#define B_ 16
#define T_ 12
#define N_ 2000
#define E_ 8000
#define M_ 32000                 // B_*N_
#define ETOT (B_*E_ + M_)        // 160000 edges incl. self loops
#define D_ 64
#define TB_ 4                    // timesteps batched per GAT launch

typedef __hip_bfloat16 bf16;
typedef unsigned short u16;

__device__ __forceinline__ float bfu(u16 u){ return __uint_as_float(((unsigned int)u)<<16); }
__device__ __forceinline__ u16 f2bu(float f){
  unsigned int x = __float_as_uint(f);
  x += 0x7FFFu + ((x >> 16) & 1u);
  return (u16)(x >> 16);
}
__device__ __forceinline__ float wred64(float x){
  x += __shfl_xor(x,1); x += __shfl_xor(x,2); x += __shfl_xor(x,4);
  x += __shfl_xor(x,8); x += __shfl_xor(x,16); x += __shfl_xor(x,32);
  return x;
}

// ---------------- weight prep (all bf16, packed for coalesced ushort4 loads) ----
// wqP u16 [L][16][3][64][4]: bf16(Wqkv[l][s*64+j][d4*4+u])           24576
// woP u16 [L][16][64][4]   : bf16(Wo[l][j*64 + d4*4+u])               8192
// w1P u16 [L][16][2][64][4]: bf16(Wf1[l][s*64+j][d4*4+u])            32768
// w2P u16 [L][32][64][4]   : bf16(Wf2[l][j*128 + hc4*4+u])           16384
__global__ void k_prep(const float* __restrict__ Wqkv, const float* __restrict__ Wo,
                       const float* __restrict__ Wf1, const float* __restrict__ Wf2,
                       u16* __restrict__ wqP, u16* __restrict__ woP,
                       u16* __restrict__ w1P, u16* __restrict__ w2P){
  int i = blockIdx.x*256 + threadIdx.x;    // 320 blocks -> 81920 threads exactly
  if(i < 24576){
    int l=i/12288, r0=i-l*12288;
    int d4=r0/768, r1=r0-d4*768;
    int s=r1/256, r2=r1-s*256;
    int jj=r2>>2, u=r2&3;
    wqP[i] = f2bu(Wqkv[l*12288 + (s*64+jj)*64 + d4*4+u]);
  } else if(i < 32768){
    int k2=i-24576;
    int l=k2/4096, r0=k2-l*4096;
    int d4=r0/256, r1=r0-d4*256, jj=r1>>2, u=r1&3;
    woP[k2] = f2bu(Wo[l*4096 + jj*64 + d4*4+u]);
  } else if(i < 65536){
    int k2=i-32768;                       // [0, 32768)
    int l=k2>>14, r0=k2&16383;
    int d4=r0>>9, r1=r0&511;
    int s=r1>>8, r2=r1&255;
    int jj=r2>>2, u=r2&3;
    w1P[k2] = f2bu(Wf1[l*8192 + (s*64+jj)*64 + d4*4+u]);
  } else {
    int k2=i-65536;                       // [0, 16384)
    int l=k2>>13, r0=k2&8191;
    int hc4=r0>>8, r1=r0&255;
    int jj=r1>>2, u=r1&3;
    w2P[k2] = f2bu(Wf2[l*8192 + jj*128 + hc4*4+u]);
  }
}

// ---------------- CSR build ----------------
__global__ void k_zero(int* __restrict__ p, int n){
  int i = blockIdx.x*256 + threadIdx.x; if(i<n) p[i]=0;
}

__global__ void k_hist(const int* __restrict__ ei, int* __restrict__ deg){
  int e = blockIdx.x*256 + threadIdx.x; if(e>=ETOT) return;
  int dst;
  if (e < B_*E_){ int b = e / E_; int k = e - b*E_; dst = ei[E_ + k] + b*N_; }
  else dst = e - B_*E_;
  atomicAdd(&deg[dst], 1);
}

__global__ void k_scan1(const int* __restrict__ deg, int* __restrict__ offs, int* __restrict__ bsums){
  __shared__ int s[256];
  int tid = threadIdx.x; int g = blockIdx.x*256 + tid;
  s[tid] = deg[g]; __syncthreads();
  for(int off=1; off<256; off<<=1){
    int a = (tid>=off) ? s[tid-off] : 0; __syncthreads();
    s[tid] += a; __syncthreads();
  }
  offs[g+1] = s[tid];
  if(tid==255) bsums[blockIdx.x] = s[255];
}

__global__ void k_scan2(const int* __restrict__ bsums, int* __restrict__ boffs){
  __shared__ int s[128];
  int tid = threadIdx.x;
  int v = (tid<125) ? bsums[tid] : 0;
  s[tid] = v; __syncthreads();
  for(int off=1; off<128; off<<=1){
    int a = (tid>=off) ? s[tid-off] : 0; __syncthreads();
    s[tid] += a; __syncthreads();
  }
  if(tid<125) boffs[tid] = s[tid] - v;
}

__global__ void k_scan3(int* __restrict__ offs, const int* __restrict__ boffs){
  int tid = threadIdx.x; int g = blockIdx.x*256 + tid;
  offs[g+1] += boffs[blockIdx.x];
  if(g==0) offs[0]=0;
}

__global__ void k_scatter(const int* __restrict__ ei, const int* __restrict__ offs,
                          int* __restrict__ cursor, int* __restrict__ csr){
  int e = blockIdx.x*256 + threadIdx.x; if(e>=ETOT) return;
  int src, dst;
  if (e < B_*E_){ int b=e/E_; int k=e-b*E_; src=ei[k]+b*N_; dst=ei[E_+k]+b*N_; }
  else { src = e - B_*E_; dst = src; }
  int pos = atomicAdd(&cursor[dst], 1);
  csr[offs[dst]+pos] = src;
}

// ---------------- fused GAT1 + GAT2 feature/score, batched over TB_ timesteps ----
__global__ __launch_bounds__(256) void k_gat12(
  const float* __restrict__ x_seq, const float* __restrict__ W1,
  const float* __restrict__ as1, const float* __restrict__ ad1, const float* __restrict__ b1,
  const float* __restrict__ W2, const float* __restrict__ as2, const float* __restrict__ ad2,
  const int* __restrict__ offs, const int* __restrict__ csr,
  u16* __restrict__ h2u, float* __restrict__ asc, float* __restrict__ adc, int t0)
{
  __shared__ float W2s[2048];       // [k=32][c=64] fp32
  __shared__ float a2s[64], a2d[64];
  int tid = threadIdx.x;
  for(int i=tid;i<2048;i+=256) W2s[i]=W2[i];
  if(tid<64){ a2s[tid]=as2[tid]; a2d[tid]=ad2[tid]; }
  __syncthreads();

  int tb = blockIdx.y, t = t0 + tb;
  int id = blockIdx.x*256 + tid;     // 500*256 = M_*4
  int m = id>>2, q = id&3;

  float sS[4], sD[4];
  #pragma unroll
  for(int h=0;h<4;h++){
    float a=0.f, d=0.f;
    #pragma unroll
    for(int c=0;c<8;c++){ float w=W1[h*8+c]; a+=w*as1[h*8+c]; d+=w*ad1[h*8+c]; }
    sS[h]=a; sD[h]=d;
  }
  unsigned um=(unsigned)m, b=um/N_, n=um-b*N_;
  const float* xsl = x_seq + (size_t)(b*T_+t)*N_;
  float xm = xsl[n];
  int e0=offs[m], e1=offs[m+1];
  // single-pass softmax (scores are O(1): no overflow risk)
  float sum[4]={0,0,0,0}, ax[4]={0,0,0,0};
  for(int e=e0;e<e1;e++){
    unsigned s=(unsigned)csr[e]; unsigned sn=s - (s/N_)*N_;
    float xv = xsl[sn];
    #pragma unroll
    for(int h=0;h<4;h++){
      float ee = xv*sS[h] + xm*sD[h]; ee = ee>0.f ? ee : 0.2f*ee;
      float w = __expf(ee); sum[h]+=w; ax[h]+=w*xv;
    }
  }
  float A[4];
  #pragma unroll
  for(int h=0;h<4;h++) A[h] = ax[h]/(sum[h]+1e-16f);

  float acc[16];
  #pragma unroll
  for(int c=0;c<16;c++) acc[c]=0.f;
  #pragma unroll
  for(int k=0;k<32;k++){
    int h = k>>3;
    float v = A[h]*W1[k] + b1[k]; v = v>0.f ? v : 0.f;   // relu(out1)
    #pragma unroll
    for(int c=0;c<16;c++) acc[c] += v*W2s[k*64 + q*16 + c];
  }
  // pack bf16, 4x uint2 stores
  uint2* hp = (uint2*)(h2u + ((size_t)tb*M_ + m)*64 + q*16);
  #pragma unroll
  for(int c2=0;c2<4;c2++){
    uint2 p;
    p.x = (unsigned)f2bu(acc[4*c2+0]) | ((unsigned)f2bu(acc[4*c2+1])<<16);
    p.y = (unsigned)f2bu(acc[4*c2+2]) | ((unsigned)f2bu(acc[4*c2+3])<<16);
    hp[c2] = p;
  }
  float ss=0.f, sd=0.f;
  #pragma unroll
  for(int c=0;c<16;c++){ ss += acc[c]*a2s[q*16+c]; sd += acc[c]*a2d[q*16+c]; }
  asc[((size_t)tb*M_+m)*4+q]=ss; adc[((size_t)tb*M_+m)*4+q]=sd;
}

// ---------------- GAT2 softmax-aggregate + bias + relu + PE, batched ----------------
__global__ __launch_bounds__(256) void k_gat2b(
  const u16* __restrict__ h2u, const float* __restrict__ asc, const float* __restrict__ adc,
  const float* __restrict__ b2, const int* __restrict__ offs, const int* __restrict__ csr,
  float* __restrict__ seq, int t0)
{
  int tb = blockIdx.y, t = t0 + tb;
  int id = blockIdx.x*256 + threadIdx.x;
  int m = id>>2, h = id&3;
  float am = adc[((size_t)tb*M_+m)*4+h];
  int e0=offs[m], e1=offs[m+1];
  float sum=0.f;
  float A[16];
  #pragma unroll
  for(int c=0;c<16;c++) A[c]=0.f;
  for(int e=e0;e<e1;e++){
    int s=csr[e];
    float ee = asc[((size_t)tb*M_+s)*4+h] + am; ee = ee>0.f ? ee : 0.2f*ee;
    float w = __expf(ee); sum += w;
    const uint2* hp = (const uint2*)(h2u + ((size_t)tb*M_ + s)*64 + h*16);
    #pragma unroll
    for(int c2=0;c2<4;c2++){
      uint2 p = hp[c2];
      A[4*c2+0] += w*bfu((u16)(p.x));
      A[4*c2+1] += w*bfu((u16)(p.x>>16));
      A[4*c2+2] += w*bfu((u16)(p.y));
      A[4*c2+3] += w*bfu((u16)(p.y>>16));
    }
  }
  float inv = 1.f/(sum + 1e-16f);
  #pragma unroll
  for(int c=0;c<16;c++){
    int ch = h*16 + c;
    float v = A[c]*inv + b2[ch]; v = v>0.f ? v : 0.f;
    float ang = (float)t * __expf(-0.14391156463f * (float)(ch & ~1));  // ln(1e4)/64
    float pe = (ch&1) ? __cosf(ang) : __sinf(ang);
    seq[((size_t)t*M_ + m)*64 + ch] = v + pe;
  }
}

// ---------------- fused attention block: Xs/QKV LDS union, 4 blocks/CU ----------------
__global__ __launch_bounds__(256) void k_attn(
  float* __restrict__ seq,
  const u16* __restrict__ wqP,   // [16][3][64][4] packed bf16
  const u16* __restrict__ woP,   // [16][64][4]    packed bf16
  const float* __restrict__ bqkv, const float* __restrict__ bo,
  const float* __restrict__ g1,   const float* __restrict__ be1)
{
  __shared__ __align__(16) float U[4][2448];   // 39168 B total
  int tid = threadIdx.x, w = tid>>6, j = tid&63;
  int m = blockIdx.x*4 + w;
  float* Uw = U[w];

  float xr[12];
  #pragma unroll
  for(int t=0;t<12;t++){ float x = seq[((size_t)t*M_ + m)*64 + j]; xr[t]=x; Uw[t*64+j]=x; }
  float bqj = bqkv[j], bkj = bqkv[64+j], bvj = bqkv[128+j];
  float boj = bo[j], gj = g1[j], bej = be1[j];
  __syncthreads();

  // phase 1: qkv projection. lane j owns column j of q,k,v for all t.
  float q[12],k[12],v[12];
  #pragma unroll
  for(int t=0;t<12;t++){ q[t]=bqj; k[t]=bkj; v[t]=bvj; }
  const ushort4* wq4 = (const ushort4*)wqP;
  #pragma unroll
  for(int d4=0; d4<16; d4++){
    float4 xv[12];
    #pragma unroll
    for(int t=0;t<12;t++) xv[t] = *(const float4*)&Uw[t*64 + d4*4];
    ushort4 aq = wq4[(d4*3+0)*64 + j];
    ushort4 ak = wq4[(d4*3+1)*64 + j];
    ushort4 av = wq4[(d4*3+2)*64 + j];
    float q0=bfu(aq.x),q1=bfu(aq.y),q2=bfu(aq.z),q3=bfu(aq.w);
    float k0=bfu(ak.x),k1=bfu(ak.y),k2=bfu(ak.z),k3=bfu(ak.w);
    float v0=bfu(av.x),v1=bfu(av.y),v2=bfu(av.z),v3=bfu(av.w);
    #pragma unroll
    for(int t=0;t<12;t++){
      q[t]+=xv[t].x*q0; q[t]+=xv[t].y*q1; q[t]+=xv[t].z*q2; q[t]+=xv[t].w*q3;
      k[t]+=xv[t].x*k0; k[t]+=xv[t].y*k1; k[t]+=xv[t].z*k2; k[t]+=xv[t].w*k3;
      v[t]+=xv[t].x*v0; v[t]+=xv[t].y*v1; v[t]+=xv[t].z*v2; v[t]+=xv[t].w*v3;
    }
  }
  #pragma unroll
  for(int t=0;t<12;t++){
    Uw[       t*68 + j]=q[t];     // QKV[0] overlays Xs — stores depend on all loads
    Uw[ 816 + t*68 + j]=k[t];
    Uw[1632 + t*68 + j]=v[t];
  }
  __syncthreads();

  // phase 2: attention. 48 lanes own (head h, time t); in-register softmax.
  if(j < 48){
    int h = j/12, t = j - h*12;
    float* qrow = &Uw[t*68 + h*16];
    float4 a0=((float4*)qrow)[0], a1=((float4*)qrow)[1], a2=((float4*)qrow)[2], a3=((float4*)qrow)[3];
    float s[12];
    #pragma unroll
    for(int t2=0;t2<12;t2++){
      const float4* kr = (const float4*)&Uw[816 + t2*68 + h*16];
      float4 c0=kr[0], c1=kr[1], c2=kr[2], c3=kr[3];
      float d = a0.x*c0.x + a0.y*c0.y + a0.z*c0.z + a0.w*c0.w
              + a1.x*c1.x + a1.y*c1.y + a1.z*c1.z + a1.w*c1.w
              + a2.x*c2.x + a2.y*c2.y + a2.z*c2.z + a2.w*c2.w
              + a3.x*c3.x + a3.y*c3.y + a3.z*c3.z + a3.w*c3.w;
      s[t2] = d*0.25f;                 // 1/sqrt(16)
    }
    float mx = s[0];
    #pragma unroll
    for(int t2=1;t2<12;t2++) mx = fmaxf(mx, s[t2]);
    float sum = 0.f;
    #pragma unroll
    for(int t2=0;t2<12;t2++){ s[t2]=__expf(s[t2]-mx); sum+=s[t2]; }
    float inv = 1.f/sum;
    float4 o0=make_float4(0,0,0,0), o1=o0, o2=o0, o3=o0;
    #pragma unroll
    for(int t2=0;t2<12;t2++){
      const float4* vr = (const float4*)&Uw[1632 + t2*68 + h*16];
      float4 c0=vr[0], c1=vr[1], c2=vr[2], c3=vr[3];
      float ww = s[t2];
      o0.x+=ww*c0.x; o0.y+=ww*c0.y; o0.z+=ww*c0.z; o0.w+=ww*c0.w;
      o1.x+=ww*c1.x; o1.y+=ww*c1.y; o1.z+=ww*c1.z; o1.w+=ww*c1.w;
      o2.x+=ww*c2.x; o2.y+=ww*c2.y; o2.z+=ww*c2.z; o2.w+=ww*c2.w;
      o3.x+=ww*c3.x; o3.y+=ww*c3.y; o3.z+=ww*c3.z; o3.w+=ww*c3.w;
    }
    o0.x*=inv;o0.y*=inv;o0.z*=inv;o0.w*=inv;
    o1.x*=inv;o1.y*=inv;o1.z*=inv;o1.w*=inv;
    o2.x*=inv;o2.y*=inv;o2.z*=inv;o2.w*=inv;
    o3.x*=inv;o3.y*=inv;o3.z*=inv;o3.w*=inv;
    ((float4*)qrow)[0]=o0; ((float4*)qrow)[1]=o1; ((float4*)qrow)[2]=o2; ((float4*)qrow)[3]=o3;
  }
  __syncthreads();

  // phase 3: Wo + residual + LN (O sits in QKV[0] region)
  float acc[12];
  #pragma unroll
  for(int t=0;t<12;t++) acc[t]=boj;
  const ushort4* wo4 = (const ushort4*)woP;
  #pragma unroll
  for(int d4=0; d4<16; d4++){
    ushort4 aw = wo4[d4*64 + j];
    float w0=bfu(aw.x), w1=bfu(aw.y), w2=bfu(aw.z), w3=bfu(aw.w);
    #pragma unroll
    for(int t=0;t<12;t++){
      float4 ov = *(const float4*)&Uw[t*68 + d4*4];
      acc[t]+=ov.x*w0; acc[t]+=ov.y*w1; acc[t]+=ov.z*w2; acc[t]+=ov.w*w3;
    }
  }
  #pragma unroll
  for(int t=0;t<12;t++){
    float x = xr[t] + acc[t];
    float mu = wred64(x)*(1.f/64.f);
    float dd = x - mu;
    float var = wred64(dd*dd)*(1.f/64.f);
    float y = dd*rsqrtf(var+1e-5f)*gj + bej;
    seq[((size_t)t*M_ + m)*64 + j] = y;
  }
}

// ---------------- FF + residual + LN: wave-private LDS dataflow ----------------
// Wave owns 12 rows. x staged in Uw[t*68+j]; hidden in Uw[816+t*128+hc].
// Per-thread live state <= ~36 floats (h0/h1 dead after LDS write) -> no spill.
// Weight reads: coalesced bf16 ushort4 (the pattern k_attn proves healthy).
__global__ __launch_bounds__(256) void k_ff(
  float* __restrict__ seq,
  const u16* __restrict__ w1P,   // [16][2][64][4] packed bf16
  const u16* __restrict__ w2P,   // [32][64][4]    packed bf16
  const float* __restrict__ bf1, const float* __restrict__ bf2,
  const float* __restrict__ g2,  const float* __restrict__ be2)
{
  __shared__ __align__(16) float U[4][2352];   // 816 + 1536 floats per wave; 37632 B
  int tid = threadIdx.x, w = tid>>6, j = tid&63;
  float* Uw = U[w];
  size_t r0 = ((size_t)blockIdx.x*4 + w)*12;   // grid 8000 -> 384000 rows

  #pragma unroll
  for(int t=0;t<12;t++) Uw[t*68 + j] = seq[(r0+t)*64 + j];

  float b1a = bf1[j], b1b = bf1[64+j];
  float b2j = bf2[j], g2j = g2[j], be2j = be2[j];

  // FF1: lane j owns hidden units j and 64+j; x broadcast (wave-uniform ds_read).
  float h0[12], h1[12];
  #pragma unroll
  for(int t=0;t<12;t++){ h0[t]=b1a; h1[t]=b1b; }
  const ushort4* w14 = (const ushort4*)w1P;
  #pragma unroll
  for(int d4=0; d4<16; d4++){
    ushort4 wa = w14[(d4*2+0)*64 + j];
    ushort4 wb = w14[(d4*2+1)*64 + j];
    float a0=bfu(wa.x),a1=bfu(wa.y),a2=bfu(wa.z),a3=bfu(wa.w);
    float c0=bfu(wb.x),c1=bfu(wb.y),c2=bfu(wb.z),c3=bfu(wb.w);
    #pragma unroll
    for(int t=0;t<12;t++){
      float4 xv = *(const float4*)&Uw[t*68 + d4*4];
      h0[t] += xv.x*a0 + xv.y*a1 + xv.z*a2 + xv.w*a3;
      h1[t] += xv.x*c0 + xv.y*c1 + xv.z*c2 + xv.w*c3;
    }
  }
  #pragma unroll
  for(int t=0;t<12;t++){
    Uw[816 + t*128 + j]      = fmaxf(h0[t], 0.f);
    Uw[816 + t*128 + 64 + j] = fmaxf(h1[t], 0.f);
  }

  // FF2: lane j owns output column j; h broadcast from Uw.
  float y2[12];
  #pragma unroll
  for(int t=0;t<12;t++) y2[t]=b2j;
  const ushort4* w24 = (const ushort4*)w2P;
  #pragma unroll
  for(int hc4=0; hc4<32; hc4++){
    ushort4 wc = w24[hc4*64 + j];
    float c0=bfu(wc.x),c1=bfu(wc.y),c2=bfu(wc.z),c3=bfu(wc.w);
    #pragma unroll
    for(int t=0;t<12;t++){
      float4 hv = *(const float4*)&Uw[816 + t*128 + hc4*4];
      y2[t] += hv.x*c0 + hv.y*c1 + hv.z*c2 + hv.w*c3;
    }
  }

  // residual (x from LDS) + LN2 + store
  #pragma unroll
  for(int t=0;t<12;t++){
    float x = Uw[t*68 + j] + y2[t];
    float mu = wred64(x)*(1.f/64.f);
    float dd = x - mu;
    float var = wred64(dd*dd)*(1.f/64.f);
    float out = dd*rsqrtf(var+1e-5f)*g2j + be2j;
    seq[(r0+t)*64 + j] = out;
  }
}

// ---------------- prediction head ----------------
__global__ void k_head(const float* __restrict__ seq, const float* __restrict__ Wh,
                       const float* __restrict__ bh, float* __restrict__ out){
  int m = blockIdx.x*256 + threadIdx.x; if(m>=M_) return;
  const float* row = seq + ((size_t)11*M_ + m)*64;
  float a0=bh[0], a1=bh[1], a2=bh[2];
  #pragma unroll
  for(int d=0;d<64;d++){
    float x = row[d];
    a0 += x*Wh[d]; a1 += x*Wh[64+d]; a2 += x*Wh[128+d];
  }
  unsigned b=(unsigned)m/N_, n=(unsigned)m-b*N_;
  out[(b*3+0)*N_+n] = a0;
  out[(b*3+1)*N_+n] = a1;
  out[(b*3+2)*N_+n] = a2;
}

extern "C" void kernel_launch(void* const* d_in, const int* in_sizes, int n_in,
                              void* d_out, int out_size, void* d_ws, size_t ws_size,
                              hipStream_t stream)
{
  const float* x_seq=(const float*)d_in[0];
  const int*   ei   =(const int*)d_in[1];
  const float* W1   =(const float*)d_in[2];
  const float* as1  =(const float*)d_in[3];
  const float* ad1  =(const float*)d_in[4];
  const float* b1   =(const float*)d_in[5];
  const float* W2   =(const float*)d_in[6];
  const float* as2  =(const float*)d_in[7];
  const float* ad2  =(const float*)d_in[8];
  const float* b2   =(const float*)d_in[9];
  const float* Wqkv =(const float*)d_in[10];
  const float* bqkv =(const float*)d_in[11];
  const float* Wo   =(const float*)d_in[12];
  const float* bo   =(const float*)d_in[13];
  const float* Wf1  =(const float*)d_in[14];
  const float* bf1p =(const float*)d_in[15];
  const float* Wf2  =(const float*)d_in[16];
  const float* bf2p =(const float*)d_in[17];
  const float* g1   =(const float*)d_in[18];
  const float* be1  =(const float*)d_in[19];
  const float* g2   =(const float*)d_in[20];
  const float* be2  =(const float*)d_in[21];
  const float* Wh   =(const float*)d_in[22];
  const float* bh   =(const float*)d_in[23];

  // workspace layout (~116 MB)
  float* seq  = (float*)d_ws;            // [T][M][64]    24,576,000 f
  float* asc  = seq  + 24576000;         // [TB_][M][4]      512,000 f
  float* adc  = asc  + 512000;           //                  512,000 f
  int* deg    = (int*)(adc + 512000);
  int* cursor = deg + M_;
  int* offs   = cursor + M_;             // M_+1 used
  int* bsums  = offs + (M_ + 2);
  int* boffs  = bsums + 128;
  int* csr    = boffs + 128;             // ETOT
  u16* h2u    = (u16*)(csr + ETOT);      // [TB_][M][64]  8,192,000 u16
  u16* wqP    = h2u + (size_t)TB_*M_*64; // 24576
  u16* woP    = wqP + 24576;             // 8192
  u16* w1P    = woP + 8192;              // 32768
  u16* w2P    = w1P + 32768;             // 16384

  k_prep   <<<dim3(320), dim3(256), 0, stream>>>(Wqkv, Wo, Wf1, Wf2, wqP, woP, w1P, w2P);

  // CSR build (edge list identical for all t)
  k_zero   <<<dim3((2*M_+255)/256), dim3(256), 0, stream>>>(deg, 2*M_);
  k_hist   <<<dim3((ETOT+255)/256), dim3(256), 0, stream>>>(ei, deg);
  k_scan1  <<<dim3(125), dim3(256), 0, stream>>>(deg, offs, bsums);
  k_scan2  <<<dim3(1),   dim3(128), 0, stream>>>(bsums, boffs);
  k_scan3  <<<dim3(125), dim3(256), 0, stream>>>(offs, boffs);
  k_scatter<<<dim3((ETOT+255)/256), dim3(256), 0, stream>>>(ei, offs, cursor, csr);

  for(int t0=0; t0<T_; t0+=TB_){
    k_gat12<<<dim3(500,TB_), dim3(256), 0, stream>>>(x_seq, W1, as1, ad1, b1,
                                                     W2, as2, ad2, offs, csr, h2u, asc, adc, t0);
    k_gat2b<<<dim3(500,TB_), dim3(256), 0, stream>>>(h2u, asc, adc, b2, offs, csr, seq, t0);
  }

  for(int i=0;i<2;i++){
    k_attn<<<dim3(8000), dim3(256), 0, stream>>>(seq,
        wqP + (size_t)i*12288, woP + (size_t)i*4096,
        bqkv + (size_t)i*192,  bo   + (size_t)i*64,
        g1   + (size_t)i*64,   be1  + (size_t)i*64);
    k_ff  <<<dim3(8000), dim3(256), 0, stream>>>(seq,
        w1P + (size_t)i*16384, w2P + (size_t)i*8192,
        bf1p + (size_t)i*128,  bf2p + (size_t)i*64,
        g2   + (size_t)i*64,   be2  + (size_t)i*64);
  }

  k_head<<<dim3(125), dim3(256), 0, stream>>>(seq, Wh, bh, (float*)d_out);
}

// Round 11
// 906.280 us; speedup vs baseline: 13.8125x; 1.5255x over previous
//
#include <hip/hip_runtime.h>
#include <hip/hip_bf16.h>

#define B_ 16
#define T_ 12
#define N_ 2000
#define E_ 8000
#define M_ 32000                 // B_*N_
#define ETOT (B_*E_ + M_)        // 160000 edges incl. self loops
#define D_ 64
#define TB_ 4                    // timesteps batched per GAT launch

typedef __hip_bfloat16 bf16;
typedef unsigned short u16;
typedef __attribute__((ext_vector_type(8))) short short8;
typedef __attribute__((ext_vector_type(4))) float f32x4;

__device__ __forceinline__ float bfu(u16 u){ return __uint_as_float(((unsigned int)u)<<16); }
__device__ __forceinline__ u16 f2bu(float f){
  unsigned int x = __float_as_uint(f);
  x += 0x7FFFu + ((x >> 16) & 1u);
  return (u16)(x >> 16);
}
__device__ __forceinline__ float wred64(float x){
  x += __shfl_xor(x,1); x += __shfl_xor(x,2); x += __shfl_xor(x,4);
  x += __shfl_xor(x,8); x += __shfl_xor(x,16); x += __shfl_xor(x,32);
  return x;
}
__device__ __forceinline__ short8 pk8(float4 a, float4 b){
  short8 r;
  r[0]=(short)f2bu(a.x); r[1]=(short)f2bu(a.y); r[2]=(short)f2bu(a.z); r[3]=(short)f2bu(a.w);
  r[4]=(short)f2bu(b.x); r[5]=(short)f2bu(b.y); r[6]=(short)f2bu(b.z); r[7]=(short)f2bu(b.w);
  return r;
}

// ---------------- weight prep ----------------
// wqP u16 [L][16][3][64][4]: bf16(Wqkv[l][s*64+j][d4*4+u])           24576
// woP u16 [L][16][64][4]   : bf16(Wo[l][j*64 + d4*4+u])               8192
// w1B u16 [L][8][2][64][8] : MFMA B-frag of Wf1 (n=lane&15,k=q*8+j)  16384
// w2B u16 [L][4][4][64][8] : MFMA B-frag of Wf2                      16384
__global__ void k_prep(const float* __restrict__ Wqkv, const float* __restrict__ Wo,
                       const float* __restrict__ Wf1, const float* __restrict__ Wf2,
                       u16* __restrict__ wqP, u16* __restrict__ woP,
                       u16* __restrict__ w1B, u16* __restrict__ w2B){
  int i = blockIdx.x*256 + threadIdx.x;    // 256 blocks -> 65536 threads exactly
  if(i < 24576){
    int l=i/12288, r0=i-l*12288;
    int d4=r0/768, r1=r0-d4*768;
    int s=r1/256, r2=r1-s*256;
    int jj=r2>>2, u=r2&3;
    wqP[i] = f2bu(Wqkv[l*12288 + (s*64+jj)*64 + d4*4+u]);
  } else if(i < 32768){
    int k2=i-24576;
    int l=k2/4096, r0=k2-l*4096;
    int d4=r0/256, r1=r0-d4*256, jj=r1>>2, u=r1&3;
    woP[k2] = f2bu(Wo[l*4096 + jj*64 + d4*4+u]);
  } else if(i < 49152){
    int k2=i-32768;                       // [0, 16384)
    int l=k2>>13, r=k2&8191;
    int nt=r>>10, r2=r&1023;
    int c=r2>>9, r3=r2&511;
    int lane=r3>>3, j=r3&7;
    int m=lane&15, q=lane>>4;
    w1B[k2] = f2bu(Wf1[l*8192 + (nt*16+m)*64 + c*32 + q*8 + j]);
  } else {
    int k2=i-49152;                       // [0, 16384)
    int l=k2>>13, r=k2&8191;
    int nt=r>>11, r2=r&2047;
    int c=r2>>9, r3=r2&511;
    int lane=r3>>3, j=r3&7;
    int m=lane&15, q=lane>>4;
    w2B[k2] = f2bu(Wf2[l*8192 + (nt*16+m)*128 + c*32 + q*8 + j]);
  }
}

// ---------------- CSR build ----------------
__global__ void k_zero(int* __restrict__ p, int n){
  int i = blockIdx.x*256 + threadIdx.x; if(i<n) p[i]=0;
}

__global__ void k_hist(const int* __restrict__ ei, int* __restrict__ deg){
  int e = blockIdx.x*256 + threadIdx.x; if(e>=ETOT) return;
  int dst;
  if (e < B_*E_){ int b = e / E_; int k = e - b*E_; dst = ei[E_ + k] + b*N_; }
  else dst = e - B_*E_;
  atomicAdd(&deg[dst], 1);
}

__global__ void k_scan1(const int* __restrict__ deg, int* __restrict__ offs, int* __restrict__ bsums){
  __shared__ int s[256];
  int tid = threadIdx.x; int g = blockIdx.x*256 + tid;
  s[tid] = deg[g]; __syncthreads();
  for(int off=1; off<256; off<<=1){
    int a = (tid>=off) ? s[tid-off] : 0; __syncthreads();
    s[tid] += a; __syncthreads();
  }
  offs[g+1] = s[tid];
  if(tid==255) bsums[blockIdx.x] = s[255];
}

__global__ void k_scan2(const int* __restrict__ bsums, int* __restrict__ boffs){
  __shared__ int s[128];
  int tid = threadIdx.x;
  int v = (tid<125) ? bsums[tid] : 0;
  s[tid] = v; __syncthreads();
  for(int off=1; off<128; off<<=1){
    int a = (tid>=off) ? s[tid-off] : 0; __syncthreads();
    s[tid] += a; __syncthreads();
  }
  if(tid<125) boffs[tid] = s[tid] - v;
}

__global__ void k_scan3(int* __restrict__ offs, const int* __restrict__ boffs){
  int tid = threadIdx.x; int g = blockIdx.x*256 + tid;
  offs[g+1] += boffs[blockIdx.x];
  if(g==0) offs[0]=0;
}

__global__ void k_scatter(const int* __restrict__ ei, const int* __restrict__ offs,
                          int* __restrict__ cursor, int* __restrict__ csr){
  int e = blockIdx.x*256 + threadIdx.x; if(e>=ETOT) return;
  int src, dst;
  if (e < B_*E_){ int b=e/E_; int k=e-b*E_; src=ei[k]+b*N_; dst=ei[E_+k]+b*N_; }
  else { src = e - B_*E_; dst = src; }
  int pos = atomicAdd(&cursor[dst], 1);
  csr[offs[dst]+pos] = src;
}

// ---------------- fused GAT1 + GAT2 feature/score, batched over TB_ timesteps ----
__global__ __launch_bounds__(256) void k_gat12(
  const float* __restrict__ x_seq, const float* __restrict__ W1,
  const float* __restrict__ as1, const float* __restrict__ ad1, const float* __restrict__ b1,
  const float* __restrict__ W2, const float* __restrict__ as2, const float* __restrict__ ad2,
  const int* __restrict__ offs, const int* __restrict__ csr,
  u16* __restrict__ h2u, float* __restrict__ asc, float* __restrict__ adc, int t0)
{
  __shared__ float W2s[2048];       // [k=32][c=64] fp32
  __shared__ float a2s[64], a2d[64];
  int tid = threadIdx.x;
  for(int i=tid;i<2048;i+=256) W2s[i]=W2[i];
  if(tid<64){ a2s[tid]=as2[tid]; a2d[tid]=ad2[tid]; }
  __syncthreads();

  int tb = blockIdx.y, t = t0 + tb;
  int id = blockIdx.x*256 + tid;     // 500*256 = M_*4
  int m = id>>2, q = id&3;

  float sS[4], sD[4];
  #pragma unroll
  for(int h=0;h<4;h++){
    float a=0.f, d=0.f;
    #pragma unroll
    for(int c=0;c<8;c++){ float w=W1[h*8+c]; a+=w*as1[h*8+c]; d+=w*ad1[h*8+c]; }
    sS[h]=a; sD[h]=d;
  }
  unsigned um=(unsigned)m, b=um/N_, n=um-b*N_;
  const float* xsl = x_seq + (size_t)(b*T_+t)*N_;
  float xm = xsl[n];
  int e0=offs[m], e1=offs[m+1];
  // single-pass softmax (scores are O(1): no overflow risk)
  float sum[4]={0,0,0,0}, ax[4]={0,0,0,0};
  for(int e=e0;e<e1;e++){
    unsigned s=(unsigned)csr[e]; unsigned sn=s - (s/N_)*N_;
    float xv = xsl[sn];
    #pragma unroll
    for(int h=0;h<4;h++){
      float ee = xv*sS[h] + xm*sD[h]; ee = ee>0.f ? ee : 0.2f*ee;
      float w = __expf(ee); sum[h]+=w; ax[h]+=w*xv;
    }
  }
  float A[4];
  #pragma unroll
  for(int h=0;h<4;h++) A[h] = ax[h]/(sum[h]+1e-16f);

  float acc[16];
  #pragma unroll
  for(int c=0;c<16;c++) acc[c]=0.f;
  #pragma unroll
  for(int k=0;k<32;k++){
    int h = k>>3;
    float v = A[h]*W1[k] + b1[k]; v = v>0.f ? v : 0.f;   // relu(out1)
    #pragma unroll
    for(int c=0;c<16;c++) acc[c] += v*W2s[k*64 + q*16 + c];
  }
  // pack bf16, 4x uint2 stores
  uint2* hp = (uint2*)(h2u + ((size_t)tb*M_ + m)*64 + q*16);
  #pragma unroll
  for(int c2=0;c2<4;c2++){
    uint2 p;
    p.x = (unsigned)f2bu(acc[4*c2+0]) | ((unsigned)f2bu(acc[4*c2+1])<<16);
    p.y = (unsigned)f2bu(acc[4*c2+2]) | ((unsigned)f2bu(acc[4*c2+3])<<16);
    hp[c2] = p;
  }
  float ss=0.f, sd=0.f;
  #pragma unroll
  for(int c=0;c<16;c++){ ss += acc[c]*a2s[q*16+c]; sd += acc[c]*a2d[q*16+c]; }
  asc[((size_t)tb*M_+m)*4+q]=ss; adc[((size_t)tb*M_+m)*4+q]=sd;
}

// ---------------- GAT2 softmax-aggregate + bias + relu + PE, batched ----------------
__global__ __launch_bounds__(256) void k_gat2b(
  const u16* __restrict__ h2u, const float* __restrict__ asc, const float* __restrict__ adc,
  const float* __restrict__ b2, const int* __restrict__ offs, const int* __restrict__ csr,
  float* __restrict__ seq, int t0)
{
  int tb = blockIdx.y, t = t0 + tb;
  int id = blockIdx.x*256 + threadIdx.x;
  int m = id>>2, h = id&3;
  float am = adc[((size_t)tb*M_+m)*4+h];
  int e0=offs[m], e1=offs[m+1];
  float sum=0.f;
  float A[16];
  #pragma unroll
  for(int c=0;c<16;c++) A[c]=0.f;
  for(int e=e0;e<e1;e++){
    int s=csr[e];
    float ee = asc[((size_t)tb*M_+s)*4+h] + am; ee = ee>0.f ? ee : 0.2f*ee;
    float w = __expf(ee); sum += w;
    const uint2* hp = (const uint2*)(h2u + ((size_t)tb*M_ + s)*64 + h*16);
    #pragma unroll
    for(int c2=0;c2<4;c2++){
      uint2 p = hp[c2];
      A[4*c2+0] += w*bfu((u16)(p.x));
      A[4*c2+1] += w*bfu((u16)(p.x>>16));
      A[4*c2+2] += w*bfu((u16)(p.y));
      A[4*c2+3] += w*bfu((u16)(p.y>>16));
    }
  }
  float inv = 1.f/(sum + 1e-16f);
  #pragma unroll
  for(int c=0;c<16;c++){
    int ch = h*16 + c;
    float v = A[c]*inv + b2[ch]; v = v>0.f ? v : 0.f;
    float ang = (float)t * __expf(-0.14391156463f * (float)(ch & ~1));  // ln(1e4)/64
    float pe = (ch&1) ? __cosf(ang) : __sinf(ang);
    seq[((size_t)t*M_ + m)*64 + ch] = v + pe;
  }
}

// ---------------- fused attention block: Xs/QKV LDS union, 4 blocks/CU ----------------
__global__ __launch_bounds__(256) void k_attn(
  float* __restrict__ seq,
  const u16* __restrict__ wqP,   // [16][3][64][4] packed bf16
  const u16* __restrict__ woP,   // [16][64][4]    packed bf16
  const float* __restrict__ bqkv, const float* __restrict__ bo,
  const float* __restrict__ g1,   const float* __restrict__ be1)
{
  __shared__ __align__(16) float U[4][2448];   // 39168 B total
  int tid = threadIdx.x, w = tid>>6, j = tid&63;
  int m = blockIdx.x*4 + w;
  float* Uw = U[w];

  float xr[12];
  #pragma unroll
  for(int t=0;t<12;t++){ float x = seq[((size_t)t*M_ + m)*64 + j]; xr[t]=x; Uw[t*64+j]=x; }
  float bqj = bqkv[j], bkj = bqkv[64+j], bvj = bqkv[128+j];
  float boj = bo[j], gj = g1[j], bej = be1[j];
  __syncthreads();

  // phase 1: qkv projection. lane j owns column j of q,k,v for all t.
  float q[12],k[12],v[12];
  #pragma unroll
  for(int t=0;t<12;t++){ q[t]=bqj; k[t]=bkj; v[t]=bvj; }
  const ushort4* wq4 = (const ushort4*)wqP;
  #pragma unroll
  for(int d4=0; d4<16; d4++){
    float4 xv[12];
    #pragma unroll
    for(int t=0;t<12;t++) xv[t] = *(const float4*)&Uw[t*64 + d4*4];
    ushort4 aq = wq4[(d4*3+0)*64 + j];
    ushort4 ak = wq4[(d4*3+1)*64 + j];
    ushort4 av = wq4[(d4*3+2)*64 + j];
    float q0=bfu(aq.x),q1=bfu(aq.y),q2=bfu(aq.z),q3=bfu(aq.w);
    float k0=bfu(ak.x),k1=bfu(ak.y),k2=bfu(ak.z),k3=bfu(ak.w);
    float v0=bfu(av.x),v1=bfu(av.y),v2=bfu(av.z),v3=bfu(av.w);
    #pragma unroll
    for(int t=0;t<12;t++){
      q[t]+=xv[t].x*q0; q[t]+=xv[t].y*q1; q[t]+=xv[t].z*q2; q[t]+=xv[t].w*q3;
      k[t]+=xv[t].x*k0; k[t]+=xv[t].y*k1; k[t]+=xv[t].z*k2; k[t]+=xv[t].w*k3;
      v[t]+=xv[t].x*v0; v[t]+=xv[t].y*v1; v[t]+=xv[t].z*v2; v[t]+=xv[t].w*v3;
    }
  }
  #pragma unroll
  for(int t=0;t<12;t++){
    Uw[       t*68 + j]=q[t];     // QKV[0] overlays Xs — stores depend on all loads
    Uw[ 816 + t*68 + j]=k[t];
    Uw[1632 + t*68 + j]=v[t];
  }
  __syncthreads();

  // phase 2: attention. 48 lanes own (head h, time t); in-register softmax.
  if(j < 48){
    int h = j/12, t = j - h*12;
    float* qrow = &Uw[t*68 + h*16];
    float4 a0=((float4*)qrow)[0], a1=((float4*)qrow)[1], a2=((float4*)qrow)[2], a3=((float4*)qrow)[3];
    float s[12];
    #pragma unroll
    for(int t2=0;t2<12;t2++){
      const float4* kr = (const float4*)&Uw[816 + t2*68 + h*16];
      float4 c0=kr[0], c1=kr[1], c2=kr[2], c3=kr[3];
      float d = a0.x*c0.x + a0.y*c0.y + a0.z*c0.z + a0.w*c0.w
              + a1.x*c1.x + a1.y*c1.y + a1.z*c1.z + a1.w*c1.w
              + a2.x*c2.x + a2.y*c2.y + a2.z*c2.z + a2.w*c2.w
              + a3.x*c3.x + a3.y*c3.y + a3.z*c3.z + a3.w*c3.w;
      s[t2] = d*0.25f;                 // 1/sqrt(16)
    }
    float mx = s[0];
    #pragma unroll
    for(int t2=1;t2<12;t2++) mx = fmaxf(mx, s[t2]);
    float sum = 0.f;
    #pragma unroll
    for(int t2=0;t2<12;t2++){ s[t2]=__expf(s[t2]-mx); sum+=s[t2]; }
    float inv = 1.f/sum;
    float4 o0=make_float4(0,0,0,0), o1=o0, o2=o0, o3=o0;
    #pragma unroll
    for(int t2=0;t2<12;t2++){
      const float4* vr = (const float4*)&Uw[1632 + t2*68 + h*16];
      float4 c0=vr[0], c1=vr[1], c2=vr[2], c3=vr[3];
      float ww = s[t2];
      o0.x+=ww*c0.x; o0.y+=ww*c0.y; o0.z+=ww*c0.z; o0.w+=ww*c0.w;
      o1.x+=ww*c1.x; o1.y+=ww*c1.y; o1.z+=ww*c1.z; o1.w+=ww*c1.w;
      o2.x+=ww*c2.x; o2.y+=ww*c2.y; o2.z+=ww*c2.z; o2.w+=ww*c2.w;
      o3.x+=ww*c3.x; o3.y+=ww*c3.y; o3.z+=ww*c3.z; o3.w+=ww*c3.w;
    }
    o0.x*=inv;o0.y*=inv;o0.z*=inv;o0.w*=inv;
    o1.x*=inv;o1.y*=inv;o1.z*=inv;o1.w*=inv;
    o2.x*=inv;o2.y*=inv;o2.z*=inv;o2.w*=inv;
    o3.x*=inv;o3.y*=inv;o3.z*=inv;o3.w*=inv;
    ((float4*)qrow)[0]=o0; ((float4*)qrow)[1]=o1; ((float4*)qrow)[2]=o2; ((float4*)qrow)[3]=o3;
  }
  __syncthreads();

  // phase 3: Wo + residual + LN (O sits in QKV[0] region)
  float acc[12];
  #pragma unroll
  for(int t=0;t<12;t++) acc[t]=boj;
  const ushort4* wo4 = (const ushort4*)woP;
  #pragma unroll
  for(int d4=0; d4<16; d4++){
    ushort4 aw = wo4[d4*64 + j];
    float w0=bfu(aw.x), w1=bfu(aw.y), w2=bfu(aw.z), w3=bfu(aw.w);
    #pragma unroll
    for(int t=0;t<12;t++){
      float4 ov = *(const float4*)&Uw[t*68 + d4*4];
      acc[t]+=ov.x*w0; acc[t]+=ov.y*w1; acc[t]+=ov.z*w2; acc[t]+=ov.w*w3;
    }
  }
  #pragma unroll
  for(int t=0;t<12;t++){
    float x = xr[t] + acc[t];
    float mu = wred64(x)*(1.f/64.f);
    float dd = x - mu;
    float var = wred64(dd*dd)*(1.f/64.f);
    float y = dd*rsqrtf(var+1e-5f)*gj + bej;
    seq[((size_t)t*M_ + m)*64 + j] = y;
  }
}

// ---------------- FF + residual + LN via MFMA ----------------
// Wave = one 16-row M-tile. FF1: X(A-frag from global) x W1(B-frag prepped) ->
// H in C-layout -> relu -> LDS [16][136] u16 (pad kills b128 bank conflict).
// FF2: H A-frags via ds_read_b128, 16 MFMAs -> Y C-layout; residual re-read from
// global (L2-hot), LN via 16-lane xor-shuffles per quad-row group.
__global__ __launch_bounds__(256) void k_ff(
  float* __restrict__ seq,
  const u16* __restrict__ w1B,   // [8][2][64][8]
  const u16* __restrict__ w2B,   // [4][4][64][8]
  const float* __restrict__ bf1, const float* __restrict__ bf2,
  const float* __restrict__ g2,  const float* __restrict__ be2)
{
  __shared__ u16 Hl[4][2176];            // [wave][16 rows x pitch 136]
  int tid = threadIdx.x, w = tid>>6, lane = tid&63;
  int m = lane&15, q = lane>>4;
  size_t r0 = ((size_t)blockIdx.x*4 + w)*16;   // grid 6000 -> 384000 rows
  u16* H = Hl[w];

  // X A-fragments (bf16): lane holds X[r0+m][c*32+q*8 .. +7] for chunks c=0,1
  const float* xb = seq + (r0+m)*64 + q*8;
  float4 x00 = *(const float4*)(xb);
  float4 x01 = *(const float4*)(xb+4);
  float4 x10 = *(const float4*)(xb+32);
  float4 x11 = *(const float4*)(xb+36);
  short8 xa0 = pk8(x00,x01), xa1 = pk8(x10,x11);

  const short8* w1v = (const short8*)w1B;
  const short8* w2v = (const short8*)w2B;

  // FF1: 8 N-tiles x (2 MFMAs over K=64) -> bias+relu -> LDS (C-layout scatter)
  #pragma unroll
  for(int nt=0; nt<8; nt++){
    f32x4 acc = {0.f,0.f,0.f,0.f};
    acc = __builtin_amdgcn_mfma_f32_16x16x32_bf16(xa0, w1v[(nt*2+0)*64+lane], acc, 0,0,0);
    acc = __builtin_amdgcn_mfma_f32_16x16x32_bf16(xa1, w1v[(nt*2+1)*64+lane], acc, 0,0,0);
    float bias = bf1[nt*16+m];
    #pragma unroll
    for(int rg=0; rg<4; rg++){
      float hv = fmaxf(acc[rg]+bias, 0.f);
      H[(q*4+rg)*136 + nt*16 + m] = f2bu(hv);
    }
  }

  // FF2: H A-frags (wave-private LDS; DS ops wave-ordered, no barrier)
  short8 ha[4];
  #pragma unroll
  for(int c=0;c<4;c++)
    ha[c] = *(const short8*)&H[m*136 + c*32 + q*8];

  float y[4][4];   // [nt2][reg]; rows q*4+reg, cols nt2*16+m
  #pragma unroll
  for(int nt2=0; nt2<4; nt2++){
    f32x4 acc = {0.f,0.f,0.f,0.f};
    #pragma unroll
    for(int c=0;c<4;c++)
      acc = __builtin_amdgcn_mfma_f32_16x16x32_bf16(ha[c], w2v[(nt2*4+c)*64+lane], acc, 0,0,0);
    int col = nt2*16+m;
    float bias = bf2[col];
    #pragma unroll
    for(int rg=0;rg<4;rg++)
      y[nt2][rg] = acc[rg] + bias + seq[(r0 + q*4 + rg)*64 + col];
  }

  // LayerNorm per row (row's 64 cols live in this quad's 16 lanes x 4 tiles)
  float mu[4], rs[4];
  #pragma unroll
  for(int rg=0;rg<4;rg++){
    float s = (y[0][rg]+y[1][rg])+(y[2][rg]+y[3][rg]);
    s += __shfl_xor(s,1); s += __shfl_xor(s,2); s += __shfl_xor(s,4); s += __shfl_xor(s,8);
    mu[rg] = s*(1.f/64.f);
    float d0=y[0][rg]-mu[rg], d1=y[1][rg]-mu[rg], d2=y[2][rg]-mu[rg], d3=y[3][rg]-mu[rg];
    float vv = (d0*d0+d1*d1)+(d2*d2+d3*d3);
    vv += __shfl_xor(vv,1); vv += __shfl_xor(vv,2); vv += __shfl_xor(vv,4); vv += __shfl_xor(vv,8);
    rs[rg] = rsqrtf(vv*(1.f/64.f)+1e-5f);
  }
  #pragma unroll
  for(int nt2=0;nt2<4;nt2++){
    int col = nt2*16+m;
    float g=g2[col], be=be2[col];
    #pragma unroll
    for(int rg=0;rg<4;rg++)
      seq[(r0 + q*4 + rg)*64 + col] = (y[nt2][rg]-mu[rg])*rs[rg]*g + be;
  }
}

// ---------------- prediction head ----------------
__global__ void k_head(const float* __restrict__ seq, const float* __restrict__ Wh,
                       const float* __restrict__ bh, float* __restrict__ out){
  int m = blockIdx.x*256 + threadIdx.x; if(m>=M_) return;
  const float* row = seq + ((size_t)11*M_ + m)*64;
  float a0=bh[0], a1=bh[1], a2=bh[2];
  #pragma unroll
  for(int d=0;d<64;d++){
    float x = row[d];
    a0 += x*Wh[d]; a1 += x*Wh[64+d]; a2 += x*Wh[128+d];
  }
  unsigned b=(unsigned)m/N_, n=(unsigned)m-b*N_;
  out[(b*3+0)*N_+n] = a0;
  out[(b*3+1)*N_+n] = a1;
  out[(b*3+2)*N_+n] = a2;
}

extern "C" void kernel_launch(void* const* d_in, const int* in_sizes, int n_in,
                              void* d_out, int out_size, void* d_ws, size_t ws_size,
                              hipStream_t stream)
{
  const float* x_seq=(const float*)d_in[0];
  const int*   ei   =(const int*)d_in[1];
  const float* W1   =(const float*)d_in[2];
  const float* as1  =(const float*)d_in[3];
  const float* ad1  =(const float*)d_in[4];
  const float* b1   =(const float*)d_in[5];
  const float* W2   =(const float*)d_in[6];
  const float* as2  =(const float*)d_in[7];
  const float* ad2  =(const float*)d_in[8];
  const float* b2   =(const float*)d_in[9];
  const float* Wqkv =(const float*)d_in[10];
  const float* bqkv =(const float*)d_in[11];
  const float* Wo   =(const float*)d_in[12];
  const float* bo   =(const float*)d_in[13];
  const float* Wf1  =(const float*)d_in[14];
  const float* bf1p =(const float*)d_in[15];
  const float* Wf2  =(const float*)d_in[16];
  const float* bf2p =(const float*)d_in[17];
  const float* g1   =(const float*)d_in[18];
  const float* be1  =(const float*)d_in[19];
  const float* g2   =(const float*)d_in[20];
  const float* be2  =(const float*)d_in[21];
  const float* Wh   =(const float*)d_in[22];
  const float* bh   =(const float*)d_in[23];

  // workspace layout (~116 MB)
  float* seq  = (float*)d_ws;            // [T][M][64]    24,576,000 f
  float* asc  = seq  + 24576000;         // [TB_][M][4]      512,000 f
  float* adc  = asc  + 512000;           //                  512,000 f
  int* deg    = (int*)(adc + 512000);
  int* cursor = deg + M_;
  int* offs   = cursor + M_;             // M_+1 used
  int* bsums  = offs + (M_ + 2);
  int* boffs  = bsums + 128;
  int* csr    = boffs + 128;             // ETOT
  u16* h2u    = (u16*)(csr + ETOT);      // [TB_][M][64]  8,192,000 u16
  u16* wqP    = h2u + (size_t)TB_*M_*64; // 24576
  u16* woP    = wqP + 24576;             // 8192
  u16* w1B    = woP + 8192;              // 16384
  u16* w2B    = w1B + 16384;             // 16384

  k_prep   <<<dim3(256), dim3(256), 0, stream>>>(Wqkv, Wo, Wf1, Wf2, wqP, woP, w1B, w2B);

  // CSR build (edge list identical for all t)
  k_zero   <<<dim3((2*M_+255)/256), dim3(256), 0, stream>>>(deg, 2*M_);
  k_hist   <<<dim3((ETOT+255)/256), dim3(256), 0, stream>>>(ei, deg);
  k_scan1  <<<dim3(125), dim3(256), 0, stream>>>(deg, offs, bsums);
  k_scan2  <<<dim3(1),   dim3(128), 0, stream>>>(bsums, boffs);
  k_scan3  <<<dim3(125), dim3(256), 0, stream>>>(offs, boffs);
  k_scatter<<<dim3((ETOT+255)/256), dim3(256), 0, stream>>>(ei, offs, cursor, csr);

  for(int t0=0; t0<T_; t0+=TB_){
    k_gat12<<<dim3(500,TB_), dim3(256), 0, stream>>>(x_seq, W1, as1, ad1, b1,
                                                     W2, as2, ad2, offs, csr, h2u, asc, adc, t0);
    k_gat2b<<<dim3(500,TB_), dim3(256), 0, stream>>>(h2u, asc, adc, b2, offs, csr, seq, t0);
  }

  for(int i=0;i<2;i++){
    k_attn<<<dim3(8000), dim3(256), 0, stream>>>(seq,
        wqP + (size_t)i*12288, woP + (size_t)i*4096,
        bqkv + (size_t)i*192,  bo   + (size_t)i*64,
        g1   + (size_t)i*64,   be1  + (size_t)i*64);
    k_ff  <<<dim3(6000), dim3(256), 0, stream>>>(seq,
        w1B + (size_t)i*8192,  w2B + (size_t)i*8192,
        bf1p + (size_t)i*128,  bf2p + (size_t)i*64,
        g2   + (size_t)i*64,   be2  + (size_t)i*64);
  }

  k_head<<<dim3(125), dim3(256), 0, stream>>>(seq, Wh, bh, (float*)d_out);
}

// Round 12
// 653.669 us; speedup vs baseline: 19.1503x; 1.3865x over previous
//
#include <hip/hip_runtime.h>
#include <hip/hip_bf16.h>

#define B_ 16
#define T_ 12
#define N_ 2000
#define E_ 8000
#define M_ 32000                 // B_*N_
#define ETOT (B_*E_ + M_)        // 160000 edges incl. self loops
#define D_ 64
#define TB_ 4                    // timesteps batched per GAT launch

typedef __hip_bfloat16 bf16;
typedef unsigned short u16;
typedef __attribute__((ext_vector_type(8))) _Float16 half8;
typedef __attribute__((ext_vector_type(4))) float f32x4;

__device__ __forceinline__ float bfu(u16 u){ return __uint_as_float(((unsigned int)u)<<16); }
__device__ __forceinline__ u16 f2bu(float f){
  unsigned int x = __float_as_uint(f);
  x += 0x7FFFu + ((x >> 16) & 1u);
  return (u16)(x >> 16);
}
__device__ __forceinline__ u16 f2h(float f){
  _Float16 h = (_Float16)f; u16 r; __builtin_memcpy(&r, &h, 2); return r;
}
__device__ __forceinline__ half8 pkh(float4 a, float4 b){
  half8 r;
  r[0]=(_Float16)a.x; r[1]=(_Float16)a.y; r[2]=(_Float16)a.z; r[3]=(_Float16)a.w;
  r[4]=(_Float16)b.x; r[5]=(_Float16)b.y; r[6]=(_Float16)b.z; r[7]=(_Float16)b.w;
  return r;
}

// ---------------- weight prep: f16 MFMA B-fragments ----------------
// B-frag layout (verified R11): value = W[n = nt*16+(lane&15)][k = c*32+(lane>>4)*8+j]
// wqB u16 [L][12][2][64][8]  24576   (Wqkv: n=qkv row 0..191, k=d)
// woB u16 [L][ 4][2][64][8]   8192   (Wo)
// w1B u16 [L][ 8][2][64][8]  16384   (Wf1)
// w2B u16 [L][ 4][4][64][8]  16384   (Wf2: k=hidden 0..127)
__global__ void k_prep(const float* __restrict__ Wqkv, const float* __restrict__ Wo,
                       const float* __restrict__ Wf1, const float* __restrict__ Wf2,
                       u16* __restrict__ wqB, u16* __restrict__ woB,
                       u16* __restrict__ w1B, u16* __restrict__ w2B){
  int i = blockIdx.x*256 + threadIdx.x;    // 256 blocks -> 65536 threads exactly
  if(i < 24576){
    int l=i/12288, r=i-l*12288;
    int nt=r>>10, r2=r&1023, c=r2>>9, r3=r2&511, lane=r3>>3, jj=r3&7;
    int m=lane&15, q=lane>>4;
    wqB[i] = f2h(Wqkv[l*12288 + (nt*16+m)*64 + c*32 + q*8 + jj]);
  } else if(i < 32768){
    int k2=i-24576;
    int l=k2>>12, r=k2&4095;
    int nt=r>>10, r2=r&1023, c=r2>>9, r3=r2&511, lane=r3>>3, jj=r3&7;
    int m=lane&15, q=lane>>4;
    woB[k2] = f2h(Wo[l*4096 + (nt*16+m)*64 + c*32 + q*8 + jj]);
  } else if(i < 49152){
    int k2=i-32768;
    int l=k2>>13, r=k2&8191;
    int nt=r>>10, r2=r&1023, c=r2>>9, r3=r2&511, lane=r3>>3, jj=r3&7;
    int m=lane&15, q=lane>>4;
    w1B[k2] = f2h(Wf1[l*8192 + (nt*16+m)*64 + c*32 + q*8 + jj]);
  } else {
    int k2=i-49152;
    int l=k2>>13, r=k2&8191;
    int nt=r>>11, r2=r&2047, c=r2>>9, r3=r2&511, lane=r3>>3, jj=r3&7;
    int m=lane&15, q=lane>>4;
    w2B[k2] = f2h(Wf2[l*8192 + (nt*16+m)*128 + c*32 + q*8 + jj]);
  }
}

// ---------------- CSR build ----------------
__global__ void k_zero(int* __restrict__ p, int n){
  int i = blockIdx.x*256 + threadIdx.x; if(i<n) p[i]=0;
}

__global__ void k_hist(const int* __restrict__ ei, int* __restrict__ deg){
  int e = blockIdx.x*256 + threadIdx.x; if(e>=ETOT) return;
  int dst;
  if (e < B_*E_){ int b = e / E_; int k = e - b*E_; dst = ei[E_ + k] + b*N_; }
  else dst = e - B_*E_;
  atomicAdd(&deg[dst], 1);
}

__global__ void k_scan1(const int* __restrict__ deg, int* __restrict__ offs, int* __restrict__ bsums){
  __shared__ int s[256];
  int tid = threadIdx.x; int g = blockIdx.x*256 + tid;
  s[tid] = deg[g]; __syncthreads();
  for(int off=1; off<256; off<<=1){
    int a = (tid>=off) ? s[tid-off] : 0; __syncthreads();
    s[tid] += a; __syncthreads();
  }
  offs[g+1] = s[tid];
  if(tid==255) bsums[blockIdx.x] = s[255];
}

__global__ void k_scan2(const int* __restrict__ bsums, int* __restrict__ boffs){
  __shared__ int s[128];
  int tid = threadIdx.x;
  int v = (tid<125) ? bsums[tid] : 0;
  s[tid] = v; __syncthreads();
  for(int off=1; off<128; off<<=1){
    int a = (tid>=off) ? s[tid-off] : 0; __syncthreads();
    s[tid] += a; __syncthreads();
  }
  if(tid<125) boffs[tid] = s[tid] - v;
}

__global__ void k_scan3(int* __restrict__ offs, const int* __restrict__ boffs){
  int tid = threadIdx.x; int g = blockIdx.x*256 + tid;
  offs[g+1] += boffs[blockIdx.x];
  if(g==0) offs[0]=0;
}

__global__ void k_scatter(const int* __restrict__ ei, const int* __restrict__ offs,
                          int* __restrict__ cursor, int* __restrict__ csr){
  int e = blockIdx.x*256 + threadIdx.x; if(e>=ETOT) return;
  int src, dst;
  if (e < B_*E_){ int b=e/E_; int k=e-b*E_; src=ei[k]+b*N_; dst=ei[E_+k]+b*N_; }
  else { src = e - B_*E_; dst = src; }
  int pos = atomicAdd(&cursor[dst], 1);
  csr[offs[dst]+pos] = src;
}

// ---------------- fused GAT1 + GAT2 feature/score, batched over TB_ timesteps ----
__global__ __launch_bounds__(256) void k_gat12(
  const float* __restrict__ x_seq, const float* __restrict__ W1,
  const float* __restrict__ as1, const float* __restrict__ ad1, const float* __restrict__ b1,
  const float* __restrict__ W2, const float* __restrict__ as2, const float* __restrict__ ad2,
  const int* __restrict__ offs, const int* __restrict__ csr,
  u16* __restrict__ h2u, float* __restrict__ asc, float* __restrict__ adc, int t0)
{
  __shared__ float W2s[2048];       // [k=32][c=64] fp32
  __shared__ float a2s[64], a2d[64];
  int tid = threadIdx.x;
  for(int i=tid;i<2048;i+=256) W2s[i]=W2[i];
  if(tid<64){ a2s[tid]=as2[tid]; a2d[tid]=ad2[tid]; }
  __syncthreads();

  int tb = blockIdx.y, t = t0 + tb;
  int id = blockIdx.x*256 + tid;     // 500*256 = M_*4
  int m = id>>2, q = id&3;

  float sS[4], sD[4];
  #pragma unroll
  for(int h=0;h<4;h++){
    float a=0.f, d=0.f;
    #pragma unroll
    for(int c=0;c<8;c++){ float w=W1[h*8+c]; a+=w*as1[h*8+c]; d+=w*ad1[h*8+c]; }
    sS[h]=a; sD[h]=d;
  }
  unsigned um=(unsigned)m, b=um/N_, n=um-b*N_;
  const float* xsl = x_seq + (size_t)(b*T_+t)*N_;
  float xm = xsl[n];
  int e0=offs[m], e1=offs[m+1];
  // single-pass softmax (scores are O(1): no overflow risk)
  float sum[4]={0,0,0,0}, ax[4]={0,0,0,0};
  for(int e=e0;e<e1;e++){
    unsigned s=(unsigned)csr[e]; unsigned sn=s - (s/N_)*N_;
    float xv = xsl[sn];
    #pragma unroll
    for(int h=0;h<4;h++){
      float ee = xv*sS[h] + xm*sD[h]; ee = ee>0.f ? ee : 0.2f*ee;
      float w = __expf(ee); sum[h]+=w; ax[h]+=w*xv;
    }
  }
  float A[4];
  #pragma unroll
  for(int h=0;h<4;h++) A[h] = ax[h]/(sum[h]+1e-16f);

  float acc[16];
  #pragma unroll
  for(int c=0;c<16;c++) acc[c]=0.f;
  #pragma unroll
  for(int k=0;k<32;k++){
    int h = k>>3;
    float v = A[h]*W1[k] + b1[k]; v = v>0.f ? v : 0.f;   // relu(out1)
    #pragma unroll
    for(int c=0;c<16;c++) acc[c] += v*W2s[k*64 + q*16 + c];
  }
  // pack bf16, 4x uint2 stores
  uint2* hp = (uint2*)(h2u + ((size_t)tb*M_ + m)*64 + q*16);
  #pragma unroll
  for(int c2=0;c2<4;c2++){
    uint2 p;
    p.x = (unsigned)f2bu(acc[4*c2+0]) | ((unsigned)f2bu(acc[4*c2+1])<<16);
    p.y = (unsigned)f2bu(acc[4*c2+2]) | ((unsigned)f2bu(acc[4*c2+3])<<16);
    hp[c2] = p;
  }
  float ss=0.f, sd=0.f;
  #pragma unroll
  for(int c=0;c<16;c++){ ss += acc[c]*a2s[q*16+c]; sd += acc[c]*a2d[q*16+c]; }
  asc[((size_t)tb*M_+m)*4+q]=ss; adc[((size_t)tb*M_+m)*4+q]=sd;
}

// ---------------- GAT2 softmax-aggregate + bias + relu + PE, batched ----------------
__global__ __launch_bounds__(256) void k_gat2b(
  const u16* __restrict__ h2u, const float* __restrict__ asc, const float* __restrict__ adc,
  const float* __restrict__ b2, const int* __restrict__ offs, const int* __restrict__ csr,
  float* __restrict__ seq, int t0)
{
  int tb = blockIdx.y, t = t0 + tb;
  int id = blockIdx.x*256 + threadIdx.x;
  int m = id>>2, h = id&3;
  float am = adc[((size_t)tb*M_+m)*4+h];
  int e0=offs[m], e1=offs[m+1];
  float sum=0.f;
  float A[16];
  #pragma unroll
  for(int c=0;c<16;c++) A[c]=0.f;
  for(int e=e0;e<e1;e++){
    int s=csr[e];
    float ee = asc[((size_t)tb*M_+s)*4+h] + am; ee = ee>0.f ? ee : 0.2f*ee;
    float w = __expf(ee); sum += w;
    const uint2* hp = (const uint2*)(h2u + ((size_t)tb*M_ + s)*64 + h*16);
    #pragma unroll
    for(int c2=0;c2<4;c2++){
      uint2 p = hp[c2];
      A[4*c2+0] += w*bfu((u16)(p.x));
      A[4*c2+1] += w*bfu((u16)(p.x>>16));
      A[4*c2+2] += w*bfu((u16)(p.y));
      A[4*c2+3] += w*bfu((u16)(p.y>>16));
    }
  }
  float inv = 1.f/(sum + 1e-16f);
  #pragma unroll
  for(int c=0;c<16;c++){
    int ch = h*16 + c;
    float v = A[c]*inv + b2[ch]; v = v>0.f ? v : 0.f;
    float ang = (float)t * __expf(-0.14391156463f * (float)(ch & ~1));  // ln(1e4)/64
    float pe = (ch&1) ? __cosf(ang) : __sinf(ang);
    seq[((size_t)t*M_ + m)*64 + ch] = v + pe;
  }
}

// ---------------- fused transformer layer, MFMA everywhere ----------------
// Wave = 1 node = 12-row M-tile (rows 12..15 padded/ignored). Wave-private LDS
// union Uw[2448]: X staged at [t*68] (Q region), QKV -> Q/K/V regions pitch 68,
// O overwrites Q, LN1-out y overwrites O, FF hidden H overlays K+V (pitch 132).
// No barriers: all cross-lane traffic is same-wave LDS (DS ops wave-ordered,
// pattern validated in R10/R11 k_ff). All GEMMs: mfma_f32_16x16x32_f16 with
// the R11-verified A/B/C fragment layouts.
__global__ __launch_bounds__(256) void k_layer(
  float* __restrict__ seq,
  const u16* __restrict__ wqB, const u16* __restrict__ woB,
  const u16* __restrict__ w1B, const u16* __restrict__ w2B,
  const float* __restrict__ bqkv, const float* __restrict__ bo,
  const float* __restrict__ bf1,  const float* __restrict__ bf2,
  const float* __restrict__ g1,   const float* __restrict__ be1,
  const float* __restrict__ g2,   const float* __restrict__ be2,
  int last)
{
  __shared__ __align__(16) float U[4][2448];   // 39168 B
  int tid=threadIdx.x, w=tid>>6, lane=tid&63;
  int m=lane&15, q=lane>>4;
  int node = blockIdx.x*4 + w;
  float* Uw = U[w];

  // stage X rows (t-major), pitch 68, coalesced
  #pragma unroll
  for(int t=0;t<12;t++) Uw[t*68 + lane] = seq[((size_t)t*M_ + node)*64 + lane];

  int mm = m<12 ? m : 11;

  // ---- QKV projection: 12 N-tiles x 2 K-chunks ----
  half8 xa0, xa1;
  {
    float4 a=*(const float4*)&Uw[mm*68 + q*8],      b=*(const float4*)&Uw[mm*68 + q*8 + 4];
    float4 c=*(const float4*)&Uw[mm*68 + 32 + q*8], d=*(const float4*)&Uw[mm*68 + 32 + q*8 + 4];
    xa0 = pkh(a,b); xa1 = pkh(c,d);
  }
  const half8* wqv = (const half8*)wqB;
  #pragma unroll
  for(int nt=0; nt<12; nt++){
    f32x4 acc={0.f,0.f,0.f,0.f};
    acc = __builtin_amdgcn_mfma_f32_16x16x32_f16(xa0, wqv[(nt*2+0)*64+lane], acc,0,0,0);
    acc = __builtin_amdgcn_mfma_f32_16x16x32_f16(xa1, wqv[(nt*2+1)*64+lane], acc,0,0,0);
    int cg = nt*16+m;                 // qkv col 0..191
    float bias = bqkv[cg];
    int s = nt>>2, lc = cg&63;
    #pragma unroll
    for(int rg=0;rg<4;rg++){
      int row=q*4+rg;
      if(row<12) Uw[s*816 + row*68 + lc] = acc[rg]+bias;
    }
  }

  // ---- attention: 48 lanes own (head h, time t); in-register softmax ----
  if(lane < 48){
    int h = lane/12, t = lane - h*12;
    float* qrow = &Uw[t*68 + h*16];
    float4 a0=((float4*)qrow)[0], a1=((float4*)qrow)[1], a2=((float4*)qrow)[2], a3=((float4*)qrow)[3];
    float s[12];
    #pragma unroll
    for(int t2=0;t2<12;t2++){
      const float4* kr = (const float4*)&Uw[816 + t2*68 + h*16];
      float4 c0=kr[0], c1=kr[1], c2=kr[2], c3=kr[3];
      float d = a0.x*c0.x + a0.y*c0.y + a0.z*c0.z + a0.w*c0.w
              + a1.x*c1.x + a1.y*c1.y + a1.z*c1.z + a1.w*c1.w
              + a2.x*c2.x + a2.y*c2.y + a2.z*c2.z + a2.w*c2.w
              + a3.x*c3.x + a3.y*c3.y + a3.z*c3.z + a3.w*c3.w;
      s[t2] = d*0.25f;                 // 1/sqrt(16)
    }
    float mx = s[0];
    #pragma unroll
    for(int t2=1;t2<12;t2++) mx = fmaxf(mx, s[t2]);
    float sum = 0.f;
    #pragma unroll
    for(int t2=0;t2<12;t2++){ s[t2]=__expf(s[t2]-mx); sum+=s[t2]; }
    float inv = 1.f/sum;
    float4 o0=make_float4(0,0,0,0), o1=o0, o2=o0, o3=o0;
    #pragma unroll
    for(int t2=0;t2<12;t2++){
      const float4* vr = (const float4*)&Uw[1632 + t2*68 + h*16];
      float4 c0=vr[0], c1=vr[1], c2=vr[2], c3=vr[3];
      float ww = s[t2];
      o0.x+=ww*c0.x; o0.y+=ww*c0.y; o0.z+=ww*c0.z; o0.w+=ww*c0.w;
      o1.x+=ww*c1.x; o1.y+=ww*c1.y; o1.z+=ww*c1.z; o1.w+=ww*c1.w;
      o2.x+=ww*c2.x; o2.y+=ww*c2.y; o2.z+=ww*c2.z; o2.w+=ww*c2.w;
      o3.x+=ww*c3.x; o3.y+=ww*c3.y; o3.z+=ww*c3.z; o3.w+=ww*c3.w;
    }
    o0.x*=inv;o0.y*=inv;o0.z*=inv;o0.w*=inv;
    o1.x*=inv;o1.y*=inv;o1.z*=inv;o1.w*=inv;
    o2.x*=inv;o2.y*=inv;o2.z*=inv;o2.w*=inv;
    o3.x*=inv;o3.y*=inv;o3.z*=inv;o3.w*=inv;
    ((float4*)qrow)[0]=o0; ((float4*)qrow)[1]=o1; ((float4*)qrow)[2]=o2; ((float4*)qrow)[3]=o3;
  }

  // ---- Wo + residual + LN1 (MFMA; O in Q region) ----
  half8 oa0, oa1;
  {
    float4 a=*(const float4*)&Uw[mm*68 + q*8],      b=*(const float4*)&Uw[mm*68 + q*8 + 4];
    float4 c=*(const float4*)&Uw[mm*68 + 32 + q*8], d=*(const float4*)&Uw[mm*68 + 32 + q*8 + 4];
    oa0 = pkh(a,b); oa1 = pkh(c,d);
  }
  const half8* wov = (const half8*)woB;
  float y[4][4];
  #pragma unroll
  for(int nt=0;nt<4;nt++){
    f32x4 acc={0.f,0.f,0.f,0.f};
    acc = __builtin_amdgcn_mfma_f32_16x16x32_f16(oa0, wov[(nt*2+0)*64+lane], acc,0,0,0);
    acc = __builtin_amdgcn_mfma_f32_16x16x32_f16(oa1, wov[(nt*2+1)*64+lane], acc,0,0,0);
    int col=nt*16+m; float bias=bo[col];
    #pragma unroll
    for(int rg=0;rg<4;rg++){
      int rc=q*4+rg; if(rc>11) rc=11;         // clamp pad rows (garbage, never stored)
      y[nt][rg] = acc[rg] + bias + seq[((size_t)rc*M_+node)*64+col];
    }
  }
  float mu[4], rs[4];
  #pragma unroll
  for(int rg=0;rg<4;rg++){
    float sm=(y[0][rg]+y[1][rg])+(y[2][rg]+y[3][rg]);
    sm+=__shfl_xor(sm,1); sm+=__shfl_xor(sm,2); sm+=__shfl_xor(sm,4); sm+=__shfl_xor(sm,8);
    mu[rg]=sm*(1.f/64.f);
    float d0=y[0][rg]-mu[rg],d1=y[1][rg]-mu[rg],d2=y[2][rg]-mu[rg],d3=y[3][rg]-mu[rg];
    float vv=(d0*d0+d1*d1)+(d2*d2+d3*d3);
    vv+=__shfl_xor(vv,1); vv+=__shfl_xor(vv,2); vv+=__shfl_xor(vv,4); vv+=__shfl_xor(vv,8);
    rs[rg]=rsqrtf(vv*(1.f/64.f)+1e-5f);
  }
  #pragma unroll
  for(int nt=0;nt<4;nt++){
    int col=nt*16+m; float g=g1[col], be=be1[col];
    #pragma unroll
    for(int rg=0;rg<4;rg++){
      float v=(y[nt][rg]-mu[rg])*rs[rg]*g+be;
      y[nt][rg]=v;                           // keep for FF residual
      int row=q*4+rg;
      if(row<12) Uw[row*68+col]=v;           // y -> Q region for FF1 A-frags
    }
  }

  // ---- FF1: 8 N-tiles x 2 K-chunks; H -> K+V regions, pitch 132 ----
  half8 ya0, ya1;
  {
    float4 a=*(const float4*)&Uw[mm*68 + q*8],      b=*(const float4*)&Uw[mm*68 + q*8 + 4];
    float4 c=*(const float4*)&Uw[mm*68 + 32 + q*8], d=*(const float4*)&Uw[mm*68 + 32 + q*8 + 4];
    ya0 = pkh(a,b); ya1 = pkh(c,d);
  }
  const half8* w1v = (const half8*)w1B;
  #pragma unroll
  for(int nt=0;nt<8;nt++){
    f32x4 acc={0.f,0.f,0.f,0.f};
    acc = __builtin_amdgcn_mfma_f32_16x16x32_f16(ya0, w1v[(nt*2+0)*64+lane], acc,0,0,0);
    acc = __builtin_amdgcn_mfma_f32_16x16x32_f16(ya1, w1v[(nt*2+1)*64+lane], acc,0,0,0);
    float bias=bf1[nt*16+m];
    #pragma unroll
    for(int rg=0;rg<4;rg++){
      int row=q*4+rg;
      if(row<12) Uw[816 + row*132 + nt*16+m] = fmaxf(acc[rg]+bias, 0.f);
    }
  }

  // ---- FF2: 4 N-tiles x 4 K-chunks; + residual y; LN2; store ----
  half8 ha[4];
  #pragma unroll
  for(int c=0;c<4;c++){
    float4 a=*(const float4*)&Uw[816 + mm*132 + c*32 + q*8];
    float4 b=*(const float4*)&Uw[816 + mm*132 + c*32 + q*8 + 4];
    ha[c]=pkh(a,b);
  }
  const half8* w2v = (const half8*)w2B;
  #pragma unroll
  for(int nt=0;nt<4;nt++){
    f32x4 acc={0.f,0.f,0.f,0.f};
    #pragma unroll
    for(int c=0;c<4;c++)
      acc = __builtin_amdgcn_mfma_f32_16x16x32_f16(ha[c], w2v[(nt*4+c)*64+lane], acc,0,0,0);
    int col=nt*16+m; float bias=bf2[col];
    #pragma unroll
    for(int rg=0;rg<4;rg++)
      y[nt][rg] = acc[rg] + bias + y[nt][rg];
  }
  #pragma unroll
  for(int rg=0;rg<4;rg++){
    float sm=(y[0][rg]+y[1][rg])+(y[2][rg]+y[3][rg]);
    sm+=__shfl_xor(sm,1); sm+=__shfl_xor(sm,2); sm+=__shfl_xor(sm,4); sm+=__shfl_xor(sm,8);
    mu[rg]=sm*(1.f/64.f);
    float d0=y[0][rg]-mu[rg],d1=y[1][rg]-mu[rg],d2=y[2][rg]-mu[rg],d3=y[3][rg]-mu[rg];
    float vv=(d0*d0+d1*d1)+(d2*d2+d3*d3);
    vv+=__shfl_xor(vv,1); vv+=__shfl_xor(vv,2); vv+=__shfl_xor(vv,4); vv+=__shfl_xor(vv,8);
    rs[rg]=rsqrtf(vv*(1.f/64.f)+1e-5f);
  }
  #pragma unroll
  for(int nt=0;nt<4;nt++){
    int col=nt*16+m; float g=g2[col], be=be2[col];
    #pragma unroll
    for(int rg=0;rg<4;rg++){
      int row=q*4+rg;
      if(row<12 && (!last || row==11))
        seq[((size_t)row*M_+node)*64+col] = (y[nt][rg]-mu[rg])*rs[rg]*g + be;
    }
  }
}

// ---------------- prediction head ----------------
__global__ void k_head(const float* __restrict__ seq, const float* __restrict__ Wh,
                       const float* __restrict__ bh, float* __restrict__ out){
  int m = blockIdx.x*256 + threadIdx.x; if(m>=M_) return;
  const float* row = seq + ((size_t)11*M_ + m)*64;
  float a0=bh[0], a1=bh[1], a2=bh[2];
  #pragma unroll
  for(int d=0;d<64;d++){
    float x = row[d];
    a0 += x*Wh[d]; a1 += x*Wh[64+d]; a2 += x*Wh[128+d];
  }
  unsigned b=(unsigned)m/N_, n=(unsigned)m-b*N_;
  out[(b*3+0)*N_+n] = a0;
  out[(b*3+1)*N_+n] = a1;
  out[(b*3+2)*N_+n] = a2;
}

extern "C" void kernel_launch(void* const* d_in, const int* in_sizes, int n_in,
                              void* d_out, int out_size, void* d_ws, size_t ws_size,
                              hipStream_t stream)
{
  const float* x_seq=(const float*)d_in[0];
  const int*   ei   =(const int*)d_in[1];
  const float* W1   =(const float*)d_in[2];
  const float* as1  =(const float*)d_in[3];
  const float* ad1  =(const float*)d_in[4];
  const float* b1   =(const float*)d_in[5];
  const float* W2   =(const float*)d_in[6];
  const float* as2  =(const float*)d_in[7];
  const float* ad2  =(const float*)d_in[8];
  const float* b2   =(const float*)d_in[9];
  const float* Wqkv =(const float*)d_in[10];
  const float* bqkv =(const float*)d_in[11];
  const float* Wo   =(const float*)d_in[12];
  const float* bo   =(const float*)d_in[13];
  const float* Wf1  =(const float*)d_in[14];
  const float* bf1p =(const float*)d_in[15];
  const float* Wf2  =(const float*)d_in[16];
  const float* bf2p =(const float*)d_in[17];
  const float* g1   =(const float*)d_in[18];
  const float* be1  =(const float*)d_in[19];
  const float* g2   =(const float*)d_in[20];
  const float* be2  =(const float*)d_in[21];
  const float* Wh   =(const float*)d_in[22];
  const float* bh   =(const float*)d_in[23];

  // workspace layout (~116 MB)
  float* seq  = (float*)d_ws;            // [T][M][64]    24,576,000 f
  float* asc  = seq  + 24576000;         // [TB_][M][4]      512,000 f
  float* adc  = asc  + 512000;           //                  512,000 f
  int* deg    = (int*)(adc + 512000);
  int* cursor = deg + M_;
  int* offs   = cursor + M_;             // M_+1 used
  int* bsums  = offs + (M_ + 2);
  int* boffs  = bsums + 128;
  int* csr    = boffs + 128;             // ETOT
  u16* h2u    = (u16*)(csr + ETOT);      // [TB_][M][64]  8,192,000 u16
  u16* wqB    = h2u + (size_t)TB_*M_*64; // 24576
  u16* woB    = wqB + 24576;             // 8192
  u16* w1B    = woB + 8192;              // 16384
  u16* w2B    = w1B + 16384;             // 16384

  k_prep   <<<dim3(256), dim3(256), 0, stream>>>(Wqkv, Wo, Wf1, Wf2, wqB, woB, w1B, w2B);

  // CSR build (edge list identical for all t)
  k_zero   <<<dim3((2*M_+255)/256), dim3(256), 0, stream>>>(deg, 2*M_);
  k_hist   <<<dim3((ETOT+255)/256), dim3(256), 0, stream>>>(ei, deg);
  k_scan1  <<<dim3(125), dim3(256), 0, stream>>>(deg, offs, bsums);
  k_scan2  <<<dim3(1),   dim3(128), 0, stream>>>(bsums, boffs);
  k_scan3  <<<dim3(125), dim3(256), 0, stream>>>(offs, boffs);
  k_scatter<<<dim3((ETOT+255)/256), dim3(256), 0, stream>>>(ei, offs, cursor, csr);

  for(int t0=0; t0<T_; t0+=TB_){
    k_gat12<<<dim3(500,TB_), dim3(256), 0, stream>>>(x_seq, W1, as1, ad1, b1,
                                                     W2, as2, ad2, offs, csr, h2u, asc, adc, t0);
    k_gat2b<<<dim3(500,TB_), dim3(256), 0, stream>>>(h2u, asc, adc, b2, offs, csr, seq, t0);
  }

  for(int i=0;i<2;i++){
    k_layer<<<dim3(8000), dim3(256), 0, stream>>>(seq,
        wqB + (size_t)i*12288, woB + (size_t)i*4096,
        w1B + (size_t)i*8192,  w2B + (size_t)i*8192,
        bqkv + (size_t)i*192,  bo   + (size_t)i*64,
        bf1p + (size_t)i*128,  bf2p + (size_t)i*64,
        g1   + (size_t)i*64,   be1  + (size_t)i*64,
        g2   + (size_t)i*64,   be2  + (size_t)i*64,
        i==1);
  }

  k_head<<<dim3(125), dim3(256), 0, stream>>>(seq, Wh, bh, (float*)d_out);
}

// Round 13
// 596.481 us; speedup vs baseline: 20.9864x; 1.0959x over previous
//
#include <hip/hip_runtime.h>
#include <hip/hip_bf16.h>

#define B_ 16
#define T_ 12
#define N_ 2000
#define E_ 8000
#define M_ 32000                 // B_*N_
#define ETOT (B_*E_ + M_)        // 160000 edges incl. self loops
#define D_ 64
#define TB_ 4                    // timesteps batched per GAT launch

typedef __hip_bfloat16 bf16;
typedef unsigned short u16;
typedef __attribute__((ext_vector_type(8))) _Float16 half8;
typedef __attribute__((ext_vector_type(4))) float f32x4;

__device__ __forceinline__ float bfu(u16 u){ return __uint_as_float(((unsigned int)u)<<16); }
__device__ __forceinline__ u16 f2bu(float f){
  unsigned int x = __float_as_uint(f);
  x += 0x7FFFu + ((x >> 16) & 1u);
  return (u16)(x >> 16);
}
__device__ __forceinline__ u16 f2h(float f){
  _Float16 h = (_Float16)f; u16 r; __builtin_memcpy(&r, &h, 2); return r;
}
__device__ __forceinline__ half8 pkh(float4 a, float4 b){
  half8 r;
  r[0]=(_Float16)a.x; r[1]=(_Float16)a.y; r[2]=(_Float16)a.z; r[3]=(_Float16)a.w;
  r[4]=(_Float16)b.x; r[5]=(_Float16)b.y; r[6]=(_Float16)b.z; r[7]=(_Float16)b.w;
  return r;
}

// ---------------- weight prep: f16 MFMA B-fragments (layout verified R11/R12) ----
// value = W[n = nt*16+(lane&15)][k = c*32+(lane>>4)*8+j]
// wqB u16 [L][12][2][64][8]  24576 | woB [L][4][2][64][8] 8192
// w1B u16 [L][ 8][2][64][8]  16384 | w2B [L][4][4][64][8] 16384
__global__ void k_prep(const float* __restrict__ Wqkv, const float* __restrict__ Wo,
                       const float* __restrict__ Wf1, const float* __restrict__ Wf2,
                       u16* __restrict__ wqB, u16* __restrict__ woB,
                       u16* __restrict__ w1B, u16* __restrict__ w2B){
  int i = blockIdx.x*256 + threadIdx.x;    // 256 blocks -> 65536 threads exactly
  if(i < 24576){
    int l=i/12288, r=i-l*12288;
    int nt=r>>10, r2=r&1023, c=r2>>9, r3=r2&511, lane=r3>>3, jj=r3&7;
    int m=lane&15, q=lane>>4;
    wqB[i] = f2h(Wqkv[l*12288 + (nt*16+m)*64 + c*32 + q*8 + jj]);
  } else if(i < 32768){
    int k2=i-24576;
    int l=k2>>12, r=k2&4095;
    int nt=r>>10, r2=r&1023, c=r2>>9, r3=r2&511, lane=r3>>3, jj=r3&7;
    int m=lane&15, q=lane>>4;
    woB[k2] = f2h(Wo[l*4096 + (nt*16+m)*64 + c*32 + q*8 + jj]);
  } else if(i < 49152){
    int k2=i-32768;
    int l=k2>>13, r=k2&8191;
    int nt=r>>10, r2=r&1023, c=r2>>9, r3=r2&511, lane=r3>>3, jj=r3&7;
    int m=lane&15, q=lane>>4;
    w1B[k2] = f2h(Wf1[l*8192 + (nt*16+m)*64 + c*32 + q*8 + jj]);
  } else {
    int k2=i-49152;
    int l=k2>>13, r=k2&8191;
    int nt=r>>11, r2=r&2047, c=r2>>9, r3=r2&511, lane=r3>>3, jj=r3&7;
    int m=lane&15, q=lane>>4;
    w2B[k2] = f2h(Wf2[l*8192 + (nt*16+m)*128 + c*32 + q*8 + jj]);
  }
}

// ---------------- CSR build ----------------
__global__ void k_zero(int* __restrict__ p, int n){
  int i = blockIdx.x*256 + threadIdx.x; if(i<n) p[i]=0;
}

__global__ void k_hist(const int* __restrict__ ei, int* __restrict__ deg){
  int e = blockIdx.x*256 + threadIdx.x; if(e>=ETOT) return;
  int dst;
  if (e < B_*E_){ int b = e / E_; int k = e - b*E_; dst = ei[E_ + k] + b*N_; }
  else dst = e - B_*E_;
  atomicAdd(&deg[dst], 1);
}

__global__ void k_scan1(const int* __restrict__ deg, int* __restrict__ offs, int* __restrict__ bsums){
  __shared__ int s[256];
  int tid = threadIdx.x; int g = blockIdx.x*256 + tid;
  s[tid] = deg[g]; __syncthreads();
  for(int off=1; off<256; off<<=1){
    int a = (tid>=off) ? s[tid-off] : 0; __syncthreads();
    s[tid] += a; __syncthreads();
  }
  offs[g+1] = s[tid];
  if(tid==255) bsums[blockIdx.x] = s[255];
}

__global__ void k_scan2(const int* __restrict__ bsums, int* __restrict__ boffs){
  __shared__ int s[128];
  int tid = threadIdx.x;
  int v = (tid<125) ? bsums[tid] : 0;
  s[tid] = v; __syncthreads();
  for(int off=1; off<128; off<<=1){
    int a = (tid>=off) ? s[tid-off] : 0; __syncthreads();
    s[tid] += a; __syncthreads();
  }
  if(tid<125) boffs[tid] = s[tid] - v;
}

__global__ void k_scan3(int* __restrict__ offs, const int* __restrict__ boffs){
  int tid = threadIdx.x; int g = blockIdx.x*256 + tid;
  offs[g+1] += boffs[blockIdx.x];
  if(g==0) offs[0]=0;
}

__global__ void k_scatter(const int* __restrict__ ei, const int* __restrict__ offs,
                          int* __restrict__ cursor, int* __restrict__ csr){
  int e = blockIdx.x*256 + threadIdx.x; if(e>=ETOT) return;
  int src, dst;
  if (e < B_*E_){ int b=e/E_; int k=e-b*E_; src=ei[k]+b*N_; dst=ei[E_+k]+b*N_; }
  else { src = e - B_*E_; dst = src; }
  int pos = atomicAdd(&cursor[dst], 1);
  csr[offs[dst]+pos] = src;
}

// ---------------- fused GAT1 + GAT2 feature/score, batched over TB_ timesteps ----
__global__ __launch_bounds__(256) void k_gat12(
  const float* __restrict__ x_seq, const float* __restrict__ W1,
  const float* __restrict__ as1, const float* __restrict__ ad1, const float* __restrict__ b1,
  const float* __restrict__ W2, const float* __restrict__ as2, const float* __restrict__ ad2,
  const int* __restrict__ offs, const int* __restrict__ csr,
  u16* __restrict__ h2u, float* __restrict__ asc, float* __restrict__ adc, int t0)
{
  __shared__ float W2s[2048];       // [k=32][c=64] fp32
  __shared__ float a2s[64], a2d[64];
  int tid = threadIdx.x;
  for(int i=tid;i<2048;i+=256) W2s[i]=W2[i];
  if(tid<64){ a2s[tid]=as2[tid]; a2d[tid]=ad2[tid]; }
  __syncthreads();

  int tb = blockIdx.y, t = t0 + tb;
  int id = blockIdx.x*256 + tid;     // 500*256 = M_*4
  int m = id>>2, q = id&3;

  float sS[4], sD[4];
  #pragma unroll
  for(int h=0;h<4;h++){
    float a=0.f, d=0.f;
    #pragma unroll
    for(int c=0;c<8;c++){ float w=W1[h*8+c]; a+=w*as1[h*8+c]; d+=w*ad1[h*8+c]; }
    sS[h]=a; sD[h]=d;
  }
  unsigned um=(unsigned)m, b=um/N_, n=um-b*N_;
  const float* xsl = x_seq + (size_t)(b*T_+t)*N_;
  float xm = xsl[n];
  int e0=offs[m], e1=offs[m+1];
  // single-pass softmax (scores are O(1): no overflow risk)
  float sum[4]={0,0,0,0}, ax[4]={0,0,0,0};
  for(int e=e0;e<e1;e++){
    unsigned s=(unsigned)csr[e]; unsigned sn=s - (s/N_)*N_;
    float xv = xsl[sn];
    #pragma unroll
    for(int h=0;h<4;h++){
      float ee = xv*sS[h] + xm*sD[h]; ee = ee>0.f ? ee : 0.2f*ee;
      float w = __expf(ee); sum[h]+=w; ax[h]+=w*xv;
    }
  }
  float A[4];
  #pragma unroll
  for(int h=0;h<4;h++) A[h] = ax[h]/(sum[h]+1e-16f);

  float acc[16];
  #pragma unroll
  for(int c=0;c<16;c++) acc[c]=0.f;
  #pragma unroll
  for(int k=0;k<32;k++){
    int h = k>>3;
    float v = A[h]*W1[k] + b1[k]; v = v>0.f ? v : 0.f;   // relu(out1)
    #pragma unroll
    for(int c=0;c<16;c++) acc[c] += v*W2s[k*64 + q*16 + c];
  }
  // pack bf16, 4x uint2 stores
  uint2* hp = (uint2*)(h2u + ((size_t)tb*M_ + m)*64 + q*16);
  #pragma unroll
  for(int c2=0;c2<4;c2++){
    uint2 p;
    p.x = (unsigned)f2bu(acc[4*c2+0]) | ((unsigned)f2bu(acc[4*c2+1])<<16);
    p.y = (unsigned)f2bu(acc[4*c2+2]) | ((unsigned)f2bu(acc[4*c2+3])<<16);
    hp[c2] = p;
  }
  float ss=0.f, sd=0.f;
  #pragma unroll
  for(int c=0;c<16;c++){ ss += acc[c]*a2s[q*16+c]; sd += acc[c]*a2d[q*16+c]; }
  asc[((size_t)tb*M_+m)*4+q]=ss; adc[((size_t)tb*M_+m)*4+q]=sd;
}

// ---------------- GAT2 softmax-aggregate + bias + relu + PE, batched ----------------
__global__ __launch_bounds__(256) void k_gat2b(
  const u16* __restrict__ h2u, const float* __restrict__ asc, const float* __restrict__ adc,
  const float* __restrict__ b2, const int* __restrict__ offs, const int* __restrict__ csr,
  float* __restrict__ seq, int t0)
{
  int tb = blockIdx.y, t = t0 + tb;
  int id = blockIdx.x*256 + threadIdx.x;
  int m = id>>2, h = id&3;
  float am = adc[((size_t)tb*M_+m)*4+h];
  int e0=offs[m], e1=offs[m+1];
  float sum=0.f;
  float A[16];
  #pragma unroll
  for(int c=0;c<16;c++) A[c]=0.f;
  for(int e=e0;e<e1;e++){
    int s=csr[e];
    float ee = asc[((size_t)tb*M_+s)*4+h] + am; ee = ee>0.f ? ee : 0.2f*ee;
    float w = __expf(ee); sum += w;
    const uint2* hp = (const uint2*)(h2u + ((size_t)tb*M_ + s)*64 + h*16);
    #pragma unroll
    for(int c2=0;c2<4;c2++){
      uint2 p = hp[c2];
      A[4*c2+0] += w*bfu((u16)(p.x));
      A[4*c2+1] += w*bfu((u16)(p.x>>16));
      A[4*c2+2] += w*bfu((u16)(p.y));
      A[4*c2+3] += w*bfu((u16)(p.y>>16));
    }
  }
  float inv = 1.f/(sum + 1e-16f);
  #pragma unroll
  for(int c=0;c<16;c++){
    int ch = h*16 + c;
    float v = A[c]*inv + b2[ch]; v = v>0.f ? v : 0.f;
    float ang = (float)t * __expf(-0.14391156463f * (float)(ch & ~1));  // ln(1e4)/64
    float pe = (ch&1) ? __cosf(ang) : __sinf(ang);
    seq[((size_t)t*M_ + m)*64 + ch] = v + pe;
  }
}

// ---------------- fused transformer layer: 192 threads / 3 waves / 4 nodes -------
// Block rows r = 0..47 map (node n=r/12, t=r%12). Wave w owns M-tile rows
// w*16..w*16+15 (100% utilized). LDS: Qf f32 [48][68] (also O, then y);
// KVH u16: K[48][72] | V[48][72], overlaid by H[48][144] after attention.
// Barriers: after QKV scatter (cross-wave K/V reads) and after O writes.
// A-frags for QKV come straight from global; residual re-read from global.
__global__ __launch_bounds__(192) void k_layer(
  float* __restrict__ seq,
  const u16* __restrict__ wqB, const u16* __restrict__ woB,
  const u16* __restrict__ w1B, const u16* __restrict__ w2B,
  const float* __restrict__ bqkv, const float* __restrict__ bo,
  const float* __restrict__ bf1,  const float* __restrict__ bf2,
  const float* __restrict__ g1,   const float* __restrict__ be1,
  const float* __restrict__ g2,   const float* __restrict__ be2,
  int last)
{
  __shared__ __align__(16) float Qf[3264];   // 48*68 f32 = 13056 B
  __shared__ __align__(16) u16  KVH[6912];   // K[0..3455] V[3456..6911] -> H[48][144]
  int tid=threadIdx.x, w=tid>>6, lane=tid&63;
  int m=lane&15, q=lane>>4;
  int r = w*16 + m;                          // this lane's A-frag block-row
  int nr = r/12, tr = r - nr*12;
  int node_r = blockIdx.x*4 + nr;

  // C-layout row metadata (rows w*16+q*4+rg)
  int trr[4]; size_t base_rr[4];
  #pragma unroll
  for(int rg=0;rg<4;rg++){
    int rc = w*16 + q*4 + rg;
    int nn = rc/12; trr[rg] = rc - nn*12;
    base_rr[rg] = ((size_t)trr[rg]*M_ + (size_t)blockIdx.x*4 + nn)*64;
  }

  // ---- QKV projection: A-frags direct from global, full 16-row tiles ----
  const float* xrow = seq + ((size_t)tr*M_ + node_r)*64;
  half8 xa0 = pkh(*(const float4*)(xrow + q*8),      *(const float4*)(xrow + q*8 + 4));
  half8 xa1 = pkh(*(const float4*)(xrow + 32 + q*8), *(const float4*)(xrow + 32 + q*8 + 4));
  const half8* wqv = (const half8*)wqB;
  #pragma unroll
  for(int nt=0; nt<12; nt++){
    f32x4 acc={0.f,0.f,0.f,0.f};
    acc = __builtin_amdgcn_mfma_f32_16x16x32_f16(xa0, wqv[(nt*2+0)*64+lane], acc,0,0,0);
    acc = __builtin_amdgcn_mfma_f32_16x16x32_f16(xa1, wqv[(nt*2+1)*64+lane], acc,0,0,0);
    int cg = nt*16+m; float bias = bqkv[cg];
    int s = nt>>2, lc = cg&63;
    #pragma unroll
    for(int rg=0;rg<4;rg++){
      int row = w*16 + q*4 + rg;
      float val = acc[rg]+bias;
      if(s==0) Qf[row*68 + lc] = val;
      else     KVH[(s-1)*3456 + row*72 + lc] = f2h(val);
    }
  }
  __syncthreads();

  // ---- attention: 192 lanes = (node an, head ah, time at) ----
  {
    int an = tid/48, rem = tid - an*48;
    int ah = rem/12, at = rem - ah*12;
    float* qrow = &Qf[(an*12+at)*68 + ah*16];
    float qv[16];
    #pragma unroll
    for(int i=0;i<4;i++){
      float4 a=((float4*)qrow)[i];
      qv[4*i]=a.x; qv[4*i+1]=a.y; qv[4*i+2]=a.z; qv[4*i+3]=a.w;
    }
    float s[12];
    #pragma unroll
    for(int t2=0;t2<12;t2++){
      const half8* kr = (const half8*)&KVH[(an*12+t2)*72 + ah*16];
      half8 k0=kr[0], k1=kr[1];
      float d=0.f;
      #pragma unroll
      for(int i=0;i<8;i++) d += qv[i]*(float)k0[i];
      #pragma unroll
      for(int i=0;i<8;i++) d += qv[8+i]*(float)k1[i];
      s[t2] = d*0.25f;                 // 1/sqrt(16)
    }
    float mx=s[0];
    #pragma unroll
    for(int t2=1;t2<12;t2++) mx=fmaxf(mx,s[t2]);
    float sum=0.f;
    #pragma unroll
    for(int t2=0;t2<12;t2++){ s[t2]=__expf(s[t2]-mx); sum+=s[t2]; }
    float inv=1.f/sum;
    float o[16];
    #pragma unroll
    for(int i=0;i<16;i++) o[i]=0.f;
    #pragma unroll
    for(int t2=0;t2<12;t2++){
      const half8* vr = (const half8*)&KVH[3456 + (an*12+t2)*72 + ah*16];
      half8 v0=vr[0], v1=vr[1];
      float ww=s[t2];
      #pragma unroll
      for(int i=0;i<8;i++) o[i]   += ww*(float)v0[i];
      #pragma unroll
      for(int i=0;i<8;i++) o[8+i] += ww*(float)v1[i];
    }
    #pragma unroll
    for(int i=0;i<4;i++)
      ((float4*)qrow)[i] = make_float4(o[4*i]*inv, o[4*i+1]*inv, o[4*i+2]*inv, o[4*i+3]*inv);
  }
  __syncthreads();

  // ---- Wo + residual + LN1 (O in Qf; reads precede y overwrite, wave-ordered) ----
  half8 oa0 = pkh(*(const float4*)&Qf[r*68 + q*8],      *(const float4*)&Qf[r*68 + q*8 + 4]);
  half8 oa1 = pkh(*(const float4*)&Qf[r*68 + 32 + q*8], *(const float4*)&Qf[r*68 + 32 + q*8 + 4]);
  const half8* wov=(const half8*)woB;
  float y[4][4];
  #pragma unroll
  for(int nt=0;nt<4;nt++){
    f32x4 acc={0.f,0.f,0.f,0.f};
    acc = __builtin_amdgcn_mfma_f32_16x16x32_f16(oa0, wov[(nt*2+0)*64+lane], acc,0,0,0);
    acc = __builtin_amdgcn_mfma_f32_16x16x32_f16(oa1, wov[(nt*2+1)*64+lane], acc,0,0,0);
    int col=nt*16+m; float bias=bo[col];
    #pragma unroll
    for(int rg=0;rg<4;rg++)
      y[nt][rg] = acc[rg] + bias + seq[base_rr[rg] + col];
  }
  float mu[4], rs[4];
  #pragma unroll
  for(int rg=0;rg<4;rg++){
    float sm=(y[0][rg]+y[1][rg])+(y[2][rg]+y[3][rg]);
    sm+=__shfl_xor(sm,1); sm+=__shfl_xor(sm,2); sm+=__shfl_xor(sm,4); sm+=__shfl_xor(sm,8);
    mu[rg]=sm*(1.f/64.f);
    float d0=y[0][rg]-mu[rg],d1=y[1][rg]-mu[rg],d2=y[2][rg]-mu[rg],d3=y[3][rg]-mu[rg];
    float vv=(d0*d0+d1*d1)+(d2*d2+d3*d3);
    vv+=__shfl_xor(vv,1); vv+=__shfl_xor(vv,2); vv+=__shfl_xor(vv,4); vv+=__shfl_xor(vv,8);
    rs[rg]=rsqrtf(vv*(1.f/64.f)+1e-5f);
  }
  #pragma unroll
  for(int nt=0;nt<4;nt++){
    int col=nt*16+m; float g=g1[col], be=be1[col];
    #pragma unroll
    for(int rg=0;rg<4;rg++){
      float v=(y[nt][rg]-mu[rg])*rs[rg]*g+be;
      y[nt][rg]=v;                                  // FF residual
      Qf[(w*16+q*4+rg)*68 + col]=v;                 // y -> wave-own rows
    }
  }

  // ---- FF1: y A-frags (wave-own), H -> KVH overlay pitch 144 u16 ----
  half8 ya0 = pkh(*(const float4*)&Qf[r*68 + q*8],      *(const float4*)&Qf[r*68 + q*8 + 4]);
  half8 ya1 = pkh(*(const float4*)&Qf[r*68 + 32 + q*8], *(const float4*)&Qf[r*68 + 32 + q*8 + 4]);
  const half8* w1v=(const half8*)w1B;
  #pragma unroll
  for(int nt=0;nt<8;nt++){
    f32x4 acc={0.f,0.f,0.f,0.f};
    acc = __builtin_amdgcn_mfma_f32_16x16x32_f16(ya0, w1v[(nt*2+0)*64+lane], acc,0,0,0);
    acc = __builtin_amdgcn_mfma_f32_16x16x32_f16(ya1, w1v[(nt*2+1)*64+lane], acc,0,0,0);
    float bias=bf1[nt*16+m];
    #pragma unroll
    for(int rg=0;rg<4;rg++)
      KVH[(w*16+q*4+rg)*144 + nt*16+m] = f2h(fmaxf(acc[rg]+bias, 0.f));
  }

  // ---- FF2: H A-frags direct half8 (no repack) + residual y + LN2 + store ----
  half8 ha[4];
  #pragma unroll
  for(int c=0;c<4;c++)
    ha[c] = *(const half8*)&KVH[r*144 + c*32 + q*8];
  const half8* w2v=(const half8*)w2B;
  #pragma unroll
  for(int nt=0;nt<4;nt++){
    f32x4 acc={0.f,0.f,0.f,0.f};
    #pragma unroll
    for(int c=0;c<4;c++)
      acc = __builtin_amdgcn_mfma_f32_16x16x32_f16(ha[c], w2v[(nt*4+c)*64+lane], acc,0,0,0);
    int col=nt*16+m; float bias=bf2[col];
    #pragma unroll
    for(int rg=0;rg<4;rg++)
      y[nt][rg] = acc[rg] + bias + y[nt][rg];
  }
  #pragma unroll
  for(int rg=0;rg<4;rg++){
    float sm=(y[0][rg]+y[1][rg])+(y[2][rg]+y[3][rg]);
    sm+=__shfl_xor(sm,1); sm+=__shfl_xor(sm,2); sm+=__shfl_xor(sm,4); sm+=__shfl_xor(sm,8);
    mu[rg]=sm*(1.f/64.f);
    float d0=y[0][rg]-mu[rg],d1=y[1][rg]-mu[rg],d2=y[2][rg]-mu[rg],d3=y[3][rg]-mu[rg];
    float vv=(d0*d0+d1*d1)+(d2*d2+d3*d3);
    vv+=__shfl_xor(vv,1); vv+=__shfl_xor(vv,2); vv+=__shfl_xor(vv,4); vv+=__shfl_xor(vv,8);
    rs[rg]=rsqrtf(vv*(1.f/64.f)+1e-5f);
  }
  #pragma unroll
  for(int nt=0;nt<4;nt++){
    int col=nt*16+m; float g=g2[col], be=be2[col];
    #pragma unroll
    for(int rg=0;rg<4;rg++){
      if(!last || trr[rg]==11)
        seq[base_rr[rg] + col] = (y[nt][rg]-mu[rg])*rs[rg]*g + be;
    }
  }
}

// ---------------- prediction head ----------------
__global__ void k_head(const float* __restrict__ seq, const float* __restrict__ Wh,
                       const float* __restrict__ bh, float* __restrict__ out){
  int m = blockIdx.x*256 + threadIdx.x; if(m>=M_) return;
  const float* row = seq + ((size_t)11*M_ + m)*64;
  float a0=bh[0], a1=bh[1], a2=bh[2];
  #pragma unroll
  for(int d=0;d<64;d++){
    float x = row[d];
    a0 += x*Wh[d]; a1 += x*Wh[64+d]; a2 += x*Wh[128+d];
  }
  unsigned b=(unsigned)m/N_, n=(unsigned)m-b*N_;
  out[(b*3+0)*N_+n] = a0;
  out[(b*3+1)*N_+n] = a1;
  out[(b*3+2)*N_+n] = a2;
}

extern "C" void kernel_launch(void* const* d_in, const int* in_sizes, int n_in,
                              void* d_out, int out_size, void* d_ws, size_t ws_size,
                              hipStream_t stream)
{
  const float* x_seq=(const float*)d_in[0];
  const int*   ei   =(const int*)d_in[1];
  const float* W1   =(const float*)d_in[2];
  const float* as1  =(const float*)d_in[3];
  const float* ad1  =(const float*)d_in[4];
  const float* b1   =(const float*)d_in[5];
  const float* W2   =(const float*)d_in[6];
  const float* as2  =(const float*)d_in[7];
  const float* ad2  =(const float*)d_in[8];
  const float* b2   =(const float*)d_in[9];
  const float* Wqkv =(const float*)d_in[10];
  const float* bqkv =(const float*)d_in[11];
  const float* Wo   =(const float*)d_in[12];
  const float* bo   =(const float*)d_in[13];
  const float* Wf1  =(const float*)d_in[14];
  const float* bf1p =(const float*)d_in[15];
  const float* Wf2  =(const float*)d_in[16];
  const float* bf2p =(const float*)d_in[17];
  const float* g1   =(const float*)d_in[18];
  const float* be1  =(const float*)d_in[19];
  const float* g2   =(const float*)d_in[20];
  const float* be2  =(const float*)d_in[21];
  const float* Wh   =(const float*)d_in[22];
  const float* bh   =(const float*)d_in[23];

  // workspace layout (~116 MB)
  float* seq  = (float*)d_ws;            // [T][M][64]    24,576,000 f
  float* asc  = seq  + 24576000;         // [TB_][M][4]      512,000 f
  float* adc  = asc  + 512000;           //                  512,000 f
  int* deg    = (int*)(adc + 512000);
  int* cursor = deg + M_;
  int* offs   = cursor + M_;             // M_+1 used
  int* bsums  = offs + (M_ + 2);
  int* boffs  = bsums + 128;
  int* csr    = boffs + 128;             // ETOT
  u16* h2u    = (u16*)(csr + ETOT);      // [TB_][M][64]  8,192,000 u16
  u16* wqB    = h2u + (size_t)TB_*M_*64; // 24576
  u16* woB    = wqB + 24576;             // 8192
  u16* w1B    = woB + 8192;              // 16384
  u16* w2B    = w1B + 16384;             // 16384

  k_prep   <<<dim3(256), dim3(256), 0, stream>>>(Wqkv, Wo, Wf1, Wf2, wqB, woB, w1B, w2B);

  // CSR build (edge list identical for all t)
  k_zero   <<<dim3((2*M_+255)/256), dim3(256), 0, stream>>>(deg, 2*M_);
  k_hist   <<<dim3((ETOT+255)/256), dim3(256), 0, stream>>>(ei, deg);
  k_scan1  <<<dim3(125), dim3(256), 0, stream>>>(deg, offs, bsums);
  k_scan2  <<<dim3(1),   dim3(128), 0, stream>>>(bsums, boffs);
  k_scan3  <<<dim3(125), dim3(256), 0, stream>>>(offs, boffs);
  k_scatter<<<dim3((ETOT+255)/256), dim3(256), 0, stream>>>(ei, offs, cursor, csr);

  for(int t0=0; t0<T_; t0+=TB_){
    k_gat12<<<dim3(500,TB_), dim3(256), 0, stream>>>(x_seq, W1, as1, ad1, b1,
                                                     W2, as2, ad2, offs, csr, h2u, asc, adc, t0);
    k_gat2b<<<dim3(500,TB_), dim3(256), 0, stream>>>(h2u, asc, adc, b2, offs, csr, seq, t0);
  }

  for(int i=0;i<2;i++){
    k_layer<<<dim3(8000), dim3(192), 0, stream>>>(seq,
        wqB + (size_t)i*12288, woB + (size_t)i*4096,
        w1B + (size_t)i*8192,  w2B + (size_t)i*8192,
        bqkv + (size_t)i*192,  bo   + (size_t)i*64,
        bf1p + (size_t)i*128,  bf2p + (size_t)i*64,
        g1   + (size_t)i*64,   be1  + (size_t)i*64,
        g2   + (size_t)i*64,   be2  + (size_t)i*64,
        i==1);
  }

  k_head<<<dim3(125), dim3(256), 0, stream>>>(seq, Wh, bh, (float*)d_out);
}

// Round 14
// 448.828 us; speedup vs baseline: 27.8904x; 1.3290x over previous
//
#include <hip/hip_runtime.h>
#include <hip/hip_bf16.h>

#define B_ 16
#define T_ 12
#define N_ 2000
#define E_ 8000
#define M_ 32000                 // B_*N_
#define ETOT (B_*E_ + M_)        // 160000 edges incl. self loops
#define D_ 64

typedef __hip_bfloat16 bf16;
typedef unsigned short u16;
typedef __attribute__((ext_vector_type(8))) _Float16 half8;
typedef __attribute__((ext_vector_type(4))) float f32x4;

__device__ __forceinline__ float bfu(u16 u){ return __uint_as_float(((unsigned int)u)<<16); }
__device__ __forceinline__ u16 f2bu(float f){
  unsigned int x = __float_as_uint(f);
  x += 0x7FFFu + ((x >> 16) & 1u);
  return (u16)(x >> 16);
}
__device__ __forceinline__ u16 f2h(float f){
  _Float16 h = (_Float16)f; u16 r; __builtin_memcpy(&r, &h, 2); return r;
}
__device__ __forceinline__ float h2f(u16 u){
  _Float16 h; __builtin_memcpy(&h, &u, 2); return (float)h;
}

// ---------------- weight prep: f16 MFMA B-fragments (layout verified R11/R12) ----
// value = W[n = nt*16+(lane&15)][k = c*32+(lane>>4)*8+j]
// wqB u16 [L][12][2][64][8]  24576 | woB [L][4][2][64][8] 8192
// w1B u16 [L][ 8][2][64][8]  16384 | w2B [L][4][4][64][8] 16384
__global__ void k_prep(const float* __restrict__ Wqkv, const float* __restrict__ Wo,
                       const float* __restrict__ Wf1, const float* __restrict__ Wf2,
                       u16* __restrict__ wqB, u16* __restrict__ woB,
                       u16* __restrict__ w1B, u16* __restrict__ w2B){
  int i = blockIdx.x*256 + threadIdx.x;    // 256 blocks -> 65536 threads exactly
  if(i < 24576){
    int l=i/12288, r=i-l*12288;
    int nt=r>>10, r2=r&1023, c=r2>>9, r3=r2&511, lane=r3>>3, jj=r3&7;
    int m=lane&15, q=lane>>4;
    wqB[i] = f2h(Wqkv[l*12288 + (nt*16+m)*64 + c*32 + q*8 + jj]);
  } else if(i < 32768){
    int k2=i-24576;
    int l=k2>>12, r=k2&4095;
    int nt=r>>10, r2=r&1023, c=r2>>9, r3=r2&511, lane=r3>>3, jj=r3&7;
    int m=lane&15, q=lane>>4;
    woB[k2] = f2h(Wo[l*4096 + (nt*16+m)*64 + c*32 + q*8 + jj]);
  } else if(i < 49152){
    int k2=i-32768;
    int l=k2>>13, r=k2&8191;
    int nt=r>>10, r2=r&1023, c=r2>>9, r3=r2&511, lane=r3>>3, jj=r3&7;
    int m=lane&15, q=lane>>4;
    w1B[k2] = f2h(Wf1[l*8192 + (nt*16+m)*64 + c*32 + q*8 + jj]);
  } else {
    int k2=i-49152;
    int l=k2>>13, r=k2&8191;
    int nt=r>>11, r2=r&2047, c=r2>>9, r3=r2&511, lane=r3>>3, jj=r3&7;
    int m=lane&15, q=lane>>4;
    w2B[k2] = f2h(Wf2[l*8192 + (nt*16+m)*128 + c*32 + q*8 + jj]);
  }
}

// ---------------- CSR build ----------------
__global__ void k_zero(int* __restrict__ p, int n){
  int i = blockIdx.x*256 + threadIdx.x; if(i<n) p[i]=0;
}

__global__ void k_hist(const int* __restrict__ ei, int* __restrict__ deg){
  int e = blockIdx.x*256 + threadIdx.x; if(e>=ETOT) return;
  int dst;
  if (e < B_*E_){ int b = e / E_; int k = e - b*E_; dst = ei[E_ + k] + b*N_; }
  else dst = e - B_*E_;
  atomicAdd(&deg[dst], 1);
}

__global__ void k_scan1(const int* __restrict__ deg, int* __restrict__ offs, int* __restrict__ bsums){
  __shared__ int s[256];
  int tid = threadIdx.x; int g = blockIdx.x*256 + tid;
  s[tid] = deg[g]; __syncthreads();
  for(int off=1; off<256; off<<=1){
    int a = (tid>=off) ? s[tid-off] : 0; __syncthreads();
    s[tid] += a; __syncthreads();
  }
  offs[g+1] = s[tid];
  if(tid==255) bsums[blockIdx.x] = s[255];
}

__global__ void k_scan2(const int* __restrict__ bsums, int* __restrict__ boffs){
  __shared__ int s[128];
  int tid = threadIdx.x;
  int v = (tid<125) ? bsums[tid] : 0;
  s[tid] = v; __syncthreads();
  for(int off=1; off<128; off<<=1){
    int a = (tid>=off) ? s[tid-off] : 0; __syncthreads();
    s[tid] += a; __syncthreads();
  }
  if(tid<125) boffs[tid] = s[tid] - v;
}

__global__ void k_scan3(int* __restrict__ offs, const int* __restrict__ boffs){
  int tid = threadIdx.x; int g = blockIdx.x*256 + tid;
  offs[g+1] += boffs[blockIdx.x];
  if(g==0) offs[0]=0;
}

__global__ void k_scatter(const int* __restrict__ ei, const int* __restrict__ offs,
                          int* __restrict__ cursor, int* __restrict__ csr){
  int e = blockIdx.x*256 + threadIdx.x; if(e>=ETOT) return;
  int src, dst;
  if (e < B_*E_){ int b=e/E_; int k=e-b*E_; src=ei[k]+b*N_; dst=ei[E_+k]+b*N_; }
  else { src = e - B_*E_; dst = src; }
  int pos = atomicAdd(&cursor[dst], 1);
  csr[offs[dst]+pos] = src;
}

// ---------------- fused GAT1 + GAT2 feature/score, all 12 timesteps ----------------
__global__ __launch_bounds__(256) void k_gat12(
  const float* __restrict__ x_seq, const float* __restrict__ W1,
  const float* __restrict__ as1, const float* __restrict__ ad1, const float* __restrict__ b1,
  const float* __restrict__ W2, const float* __restrict__ as2, const float* __restrict__ ad2,
  const int* __restrict__ offs, const int* __restrict__ csr,
  u16* __restrict__ h2u, float* __restrict__ asc, float* __restrict__ adc)
{
  __shared__ float W2s[2048];       // [k=32][c=64] fp32
  __shared__ float a2s[64], a2d[64];
  int tid = threadIdx.x;
  for(int i=tid;i<2048;i+=256) W2s[i]=W2[i];
  if(tid<64){ a2s[tid]=as2[tid]; a2d[tid]=ad2[tid]; }
  __syncthreads();

  int t = blockIdx.y;
  int id = blockIdx.x*256 + tid;     // 500*256 = M_*4
  int m = id>>2, q = id&3;

  float sS[4], sD[4];
  #pragma unroll
  for(int h=0;h<4;h++){
    float a=0.f, d=0.f;
    #pragma unroll
    for(int c=0;c<8;c++){ float w=W1[h*8+c]; a+=w*as1[h*8+c]; d+=w*ad1[h*8+c]; }
    sS[h]=a; sD[h]=d;
  }
  unsigned um=(unsigned)m, b=um/N_, n=um-b*N_;
  const float* xsl = x_seq + (size_t)(b*T_+t)*N_;
  float xm = xsl[n];
  int e0=offs[m], e1=offs[m+1];
  // single-pass softmax (scores are O(1): no overflow risk)
  float sum[4]={0,0,0,0}, ax[4]={0,0,0,0};
  for(int e=e0;e<e1;e++){
    unsigned s=(unsigned)csr[e]; unsigned sn=s - (s/N_)*N_;
    float xv = xsl[sn];
    #pragma unroll
    for(int h=0;h<4;h++){
      float ee = xv*sS[h] + xm*sD[h]; ee = ee>0.f ? ee : 0.2f*ee;
      float w = __expf(ee); sum[h]+=w; ax[h]+=w*xv;
    }
  }
  float A[4];
  #pragma unroll
  for(int h=0;h<4;h++) A[h] = ax[h]/(sum[h]+1e-16f);

  float acc[16];
  #pragma unroll
  for(int c=0;c<16;c++) acc[c]=0.f;
  #pragma unroll
  for(int k=0;k<32;k++){
    int h = k>>3;
    float v = A[h]*W1[k] + b1[k]; v = v>0.f ? v : 0.f;   // relu(out1)
    #pragma unroll
    for(int c=0;c<16;c++) acc[c] += v*W2s[k*64 + q*16 + c];
  }
  // pack bf16, 4x uint2 stores
  uint2* hp = (uint2*)(h2u + ((size_t)t*M_ + m)*64 + q*16);
  #pragma unroll
  for(int c2=0;c2<4;c2++){
    uint2 p;
    p.x = (unsigned)f2bu(acc[4*c2+0]) | ((unsigned)f2bu(acc[4*c2+1])<<16);
    p.y = (unsigned)f2bu(acc[4*c2+2]) | ((unsigned)f2bu(acc[4*c2+3])<<16);
    hp[c2] = p;
  }
  float ss=0.f, sd=0.f;
  #pragma unroll
  for(int c=0;c<16;c++){ ss += acc[c]*a2s[q*16+c]; sd += acc[c]*a2d[q*16+c]; }
  asc[((size_t)t*M_+m)*4+q]=ss; adc[((size_t)t*M_+m)*4+q]=sd;
}

// ---------------- GAT2 softmax-aggregate + bias + relu + PE; seq f16 out ----------
__global__ __launch_bounds__(256) void k_gat2b(
  const u16* __restrict__ h2u, const float* __restrict__ asc, const float* __restrict__ adc,
  const float* __restrict__ b2, const int* __restrict__ offs, const int* __restrict__ csr,
  u16* __restrict__ seq)
{
  int t = blockIdx.y;
  int id = blockIdx.x*256 + threadIdx.x;
  int m = id>>2, h = id&3;
  float am = adc[((size_t)t*M_+m)*4+h];
  int e0=offs[m], e1=offs[m+1];
  float sum=0.f;
  float A[16];
  #pragma unroll
  for(int c=0;c<16;c++) A[c]=0.f;
  for(int e=e0;e<e1;e++){
    int s=csr[e];
    float ee = asc[((size_t)t*M_+s)*4+h] + am; ee = ee>0.f ? ee : 0.2f*ee;
    float w = __expf(ee); sum += w;
    const uint2* hp = (const uint2*)(h2u + ((size_t)t*M_ + s)*64 + h*16);
    #pragma unroll
    for(int c2=0;c2<4;c2++){
      uint2 p = hp[c2];
      A[4*c2+0] += w*bfu((u16)(p.x));
      A[4*c2+1] += w*bfu((u16)(p.x>>16));
      A[4*c2+2] += w*bfu((u16)(p.y));
      A[4*c2+3] += w*bfu((u16)(p.y>>16));
    }
  }
  float inv = 1.f/(sum + 1e-16f);
  #pragma unroll
  for(int c=0;c<16;c++){
    int ch = h*16 + c;
    float v = A[c]*inv + b2[ch]; v = v>0.f ? v : 0.f;
    float ang = (float)t * __expf(-0.14391156463f * (float)(ch & ~1));  // ln(1e4)/64
    float pe = (ch&1) ? __cosf(ang) : __sinf(ang);
    seq[((size_t)t*M_ + m)*64 + ch] = f2h(v + pe);
  }
}

// ---------------- fused transformer layer: all-f16 dataflow ----------------
// 192 threads / 3 waves / 4 nodes (48 rows, full 16-row M-tiles). seq is f16 so
// QKV A-frags load directly (half8) from global. LDS: QKV u16 [3][48][72];
// Q region reused for O then LN1-y (f16 => Wo/FF1 A-frags are direct ds_read_b128,
// zero repack); K/V region overlaid by H [48][136]. Barriers: after QKV scatter
// and after attention O-writes (cross-wave); FF phases wave-ordered.
__global__ __launch_bounds__(192) void k_layer(
  u16* __restrict__ seq,
  const u16* __restrict__ wqB, const u16* __restrict__ woB,
  const u16* __restrict__ w1B, const u16* __restrict__ w2B,
  const float* __restrict__ bqkv, const float* __restrict__ bo,
  const float* __restrict__ bf1,  const float* __restrict__ bf2,
  const float* __restrict__ g1,   const float* __restrict__ be1,
  const float* __restrict__ g2,   const float* __restrict__ be2,
  int last)
{
  __shared__ __align__(16) u16 QKV[10368];   // 3*48*72 u16 = 20736 B
  u16* Hd = QKV + 3456;                      // H[48][136] overlays K,V
  int tid=threadIdx.x, w=tid>>6, lane=tid&63;
  int m=lane&15, q=lane>>4;
  int r = w*16 + m;                          // this lane's A-frag block-row
  int nr = r/12, tr = r - nr*12;
  int node_r = blockIdx.x*4 + nr;

  // C-layout row metadata (rows w*16+q*4+rg)
  int trr[4]; size_t base_rr[4];
  #pragma unroll
  for(int rg=0;rg<4;rg++){
    int rc = w*16 + q*4 + rg;
    int nn = rc/12; trr[rg] = rc - nn*12;
    base_rr[rg] = ((size_t)trr[rg]*M_ + (size_t)blockIdx.x*4 + nn)*64;
  }

  // ---- QKV projection: direct half8 A-frags from f16 global ----
  const u16* xrow = seq + ((size_t)tr*M_ + node_r)*64;
  half8 xa0 = *(const half8*)(xrow + q*8);
  half8 xa1 = *(const half8*)(xrow + 32 + q*8);
  const half8* wqv = (const half8*)wqB;
  #pragma unroll
  for(int nt=0; nt<12; nt++){
    f32x4 acc={0.f,0.f,0.f,0.f};
    acc = __builtin_amdgcn_mfma_f32_16x16x32_f16(xa0, wqv[(nt*2+0)*64+lane], acc,0,0,0);
    acc = __builtin_amdgcn_mfma_f32_16x16x32_f16(xa1, wqv[(nt*2+1)*64+lane], acc,0,0,0);
    int cg = nt*16+m; float bias = bqkv[cg];
    int s = nt>>2, lc = cg&63;
    #pragma unroll
    for(int rg=0;rg<4;rg++){
      int row = w*16 + q*4 + rg;
      QKV[s*3456 + row*72 + lc] = f2h(acc[rg]+bias);
    }
  }
  __syncthreads();

  // ---- attention: 192 lanes = (node an, head ah, time at) ----
  {
    int an = tid/48, rem = tid - an*48;
    int ah = rem/12, at = rem - ah*12;
    u16* qrow = &QKV[(an*12+at)*72 + ah*16];
    half8 q0 = ((const half8*)qrow)[0], q1 = ((const half8*)qrow)[1];
    float qv[16];
    #pragma unroll
    for(int i=0;i<8;i++){ qv[i]=(float)q0[i]; qv[8+i]=(float)q1[i]; }
    float s[12];
    #pragma unroll
    for(int t2=0;t2<12;t2++){
      const half8* kr = (const half8*)&QKV[3456 + (an*12+t2)*72 + ah*16];
      half8 k0=kr[0], k1=kr[1];
      float d=0.f;
      #pragma unroll
      for(int i=0;i<8;i++) d += qv[i]*(float)k0[i];
      #pragma unroll
      for(int i=0;i<8;i++) d += qv[8+i]*(float)k1[i];
      s[t2] = d*0.25f;                 // 1/sqrt(16)
    }
    float mx=s[0];
    #pragma unroll
    for(int t2=1;t2<12;t2++) mx=fmaxf(mx,s[t2]);
    float sum=0.f;
    #pragma unroll
    for(int t2=0;t2<12;t2++){ s[t2]=__expf(s[t2]-mx); sum+=s[t2]; }
    float inv=1.f/sum;
    float o[16];
    #pragma unroll
    for(int i=0;i<16;i++) o[i]=0.f;
    #pragma unroll
    for(int t2=0;t2<12;t2++){
      const half8* vr = (const half8*)&QKV[6912 + (an*12+t2)*72 + ah*16];
      half8 v0=vr[0], v1=vr[1];
      float ww=s[t2];
      #pragma unroll
      for(int i=0;i<8;i++) o[i]   += ww*(float)v0[i];
      #pragma unroll
      for(int i=0;i<8;i++) o[8+i] += ww*(float)v1[i];
    }
    half8 o0h, o1h;
    #pragma unroll
    for(int i=0;i<8;i++){ o0h[i]=(_Float16)(o[i]*inv); o1h[i]=(_Float16)(o[8+i]*inv); }
    ((half8*)qrow)[0]=o0h; ((half8*)qrow)[1]=o1h;
  }
  __syncthreads();

  // ---- Wo + residual + LN1 (O in Q region; direct half8 A-frags) ----
  half8 oa0 = *(const half8*)&QKV[r*72 + q*8];
  half8 oa1 = *(const half8*)&QKV[r*72 + 32 + q*8];
  const half8* wov=(const half8*)woB;
  float y[4][4];
  #pragma unroll
  for(int nt=0;nt<4;nt++){
    f32x4 acc={0.f,0.f,0.f,0.f};
    acc = __builtin_amdgcn_mfma_f32_16x16x32_f16(oa0, wov[(nt*2+0)*64+lane], acc,0,0,0);
    acc = __builtin_amdgcn_mfma_f32_16x16x32_f16(oa1, wov[(nt*2+1)*64+lane], acc,0,0,0);
    int col=nt*16+m; float bias=bo[col];
    #pragma unroll
    for(int rg=0;rg<4;rg++)
      y[nt][rg] = acc[rg] + bias + h2f(seq[base_rr[rg] + col]);
  }
  float mu[4], rs[4];
  #pragma unroll
  for(int rg=0;rg<4;rg++){
    float sm=(y[0][rg]+y[1][rg])+(y[2][rg]+y[3][rg]);
    sm+=__shfl_xor(sm,1); sm+=__shfl_xor(sm,2); sm+=__shfl_xor(sm,4); sm+=__shfl_xor(sm,8);
    mu[rg]=sm*(1.f/64.f);
    float d0=y[0][rg]-mu[rg],d1=y[1][rg]-mu[rg],d2=y[2][rg]-mu[rg],d3=y[3][rg]-mu[rg];
    float vv=(d0*d0+d1*d1)+(d2*d2+d3*d3);
    vv+=__shfl_xor(vv,1); vv+=__shfl_xor(vv,2); vv+=__shfl_xor(vv,4); vv+=__shfl_xor(vv,8);
    rs[rg]=rsqrtf(vv*(1.f/64.f)+1e-5f);
  }
  #pragma unroll
  for(int nt=0;nt<4;nt++){
    int col=nt*16+m; float g=g1[col], be=be1[col];
    #pragma unroll
    for(int rg=0;rg<4;rg++){
      float v=(y[nt][rg]-mu[rg])*rs[rg]*g+be;
      y[nt][rg]=v;                                  // FF residual (f32)
      QKV[(w*16+q*4+rg)*72 + col]=f2h(v);           // y -> wave-own rows (f16)
    }
  }

  // ---- FF1: y A-frags (wave-own, direct half8); H -> pitch-136 overlay ----
  half8 ya0 = *(const half8*)&QKV[r*72 + q*8];
  half8 ya1 = *(const half8*)&QKV[r*72 + 32 + q*8];
  const half8* w1v=(const half8*)w1B;
  #pragma unroll
  for(int nt=0;nt<8;nt++){
    f32x4 acc={0.f,0.f,0.f,0.f};
    acc = __builtin_amdgcn_mfma_f32_16x16x32_f16(ya0, w1v[(nt*2+0)*64+lane], acc,0,0,0);
    acc = __builtin_amdgcn_mfma_f32_16x16x32_f16(ya1, w1v[(nt*2+1)*64+lane], acc,0,0,0);
    float bias=bf1[nt*16+m];
    #pragma unroll
    for(int rg=0;rg<4;rg++)
      Hd[(w*16+q*4+rg)*136 + nt*16+m] = f2h(fmaxf(acc[rg]+bias, 0.f));
  }

  // ---- FF2: H A-frags direct half8 + residual y + LN2 + store f16 ----
  half8 ha[4];
  #pragma unroll
  for(int c=0;c<4;c++)
    ha[c] = *(const half8*)&Hd[r*136 + c*32 + q*8];
  const half8* w2v=(const half8*)w2B;
  #pragma unroll
  for(int nt=0;nt<4;nt++){
    f32x4 acc={0.f,0.f,0.f,0.f};
    #pragma unroll
    for(int c=0;c<4;c++)
      acc = __builtin_amdgcn_mfma_f32_16x16x32_f16(ha[c], w2v[(nt*4+c)*64+lane], acc,0,0,0);
    int col=nt*16+m; float bias=bf2[col];
    #pragma unroll
    for(int rg=0;rg<4;rg++)
      y[nt][rg] = acc[rg] + bias + y[nt][rg];
  }
  #pragma unroll
  for(int rg=0;rg<4;rg++){
    float sm=(y[0][rg]+y[1][rg])+(y[2][rg]+y[3][rg]);
    sm+=__shfl_xor(sm,1); sm+=__shfl_xor(sm,2); sm+=__shfl_xor(sm,4); sm+=__shfl_xor(sm,8);
    mu[rg]=sm*(1.f/64.f);
    float d0=y[0][rg]-mu[rg],d1=y[1][rg]-mu[rg],d2=y[2][rg]-mu[rg],d3=y[3][rg]-mu[rg];
    float vv=(d0*d0+d1*d1)+(d2*d2+d3*d3);
    vv+=__shfl_xor(vv,1); vv+=__shfl_xor(vv,2); vv+=__shfl_xor(vv,4); vv+=__shfl_xor(vv,8);
    rs[rg]=rsqrtf(vv*(1.f/64.f)+1e-5f);
  }
  #pragma unroll
  for(int nt=0;nt<4;nt++){
    int col=nt*16+m; float g=g2[col], be=be2[col];
    #pragma unroll
    for(int rg=0;rg<4;rg++){
      if(!last || trr[rg]==11)
        seq[base_rr[rg] + col] = f2h((y[nt][rg]-mu[rg])*rs[rg]*g + be);
    }
  }
}

// ---------------- prediction head (f16 seq in) ----------------
__global__ void k_head(const u16* __restrict__ seq, const float* __restrict__ Wh,
                       const float* __restrict__ bh, float* __restrict__ out){
  int m = blockIdx.x*256 + threadIdx.x; if(m>=M_) return;
  const u16* row = seq + ((size_t)11*M_ + m)*64;
  float a0=bh[0], a1=bh[1], a2=bh[2];
  #pragma unroll
  for(int d=0;d<64;d++){
    float x = h2f(row[d]);
    a0 += x*Wh[d]; a1 += x*Wh[64+d]; a2 += x*Wh[128+d];
  }
  unsigned b=(unsigned)m/N_, n=(unsigned)m-b*N_;
  out[(b*3+0)*N_+n] = a0;
  out[(b*3+1)*N_+n] = a1;
  out[(b*3+2)*N_+n] = a2;
}

extern "C" void kernel_launch(void* const* d_in, const int* in_sizes, int n_in,
                              void* d_out, int out_size, void* d_ws, size_t ws_size,
                              hipStream_t stream)
{
  const float* x_seq=(const float*)d_in[0];
  const int*   ei   =(const int*)d_in[1];
  const float* W1   =(const float*)d_in[2];
  const float* as1  =(const float*)d_in[3];
  const float* ad1  =(const float*)d_in[4];
  const float* b1   =(const float*)d_in[5];
  const float* W2   =(const float*)d_in[6];
  const float* as2  =(const float*)d_in[7];
  const float* ad2  =(const float*)d_in[8];
  const float* b2   =(const float*)d_in[9];
  const float* Wqkv =(const float*)d_in[10];
  const float* bqkv =(const float*)d_in[11];
  const float* Wo   =(const float*)d_in[12];
  const float* bo   =(const float*)d_in[13];
  const float* Wf1  =(const float*)d_in[14];
  const float* bf1p =(const float*)d_in[15];
  const float* Wf2  =(const float*)d_in[16];
  const float* bf2p =(const float*)d_in[17];
  const float* g1   =(const float*)d_in[18];
  const float* be1  =(const float*)d_in[19];
  const float* g2   =(const float*)d_in[20];
  const float* be2  =(const float*)d_in[21];
  const float* Wh   =(const float*)d_in[22];
  const float* bh   =(const float*)d_in[23];

  // workspace layout (~112 MB)
  u16* seqh   = (u16*)d_ws;                     // [T][M][64] f16  24,576,000 u16
  float* asc  = (float*)(seqh + 24576000);      // [T][M][4]        1,536,000 f
  float* adc  = asc + 1536000;                  //                  1,536,000 f
  int* deg    = (int*)(adc + 1536000);
  int* cursor = deg + M_;
  int* offs   = cursor + M_;                    // M_+1 used
  int* bsums  = offs + (M_ + 2);
  int* boffs  = bsums + 128;
  int* csr    = boffs + 128;                    // ETOT
  u16* h2u    = (u16*)(csr + ETOT);             // [T][M][64]   24,576,000 u16
  u16* wqB    = h2u + (size_t)T_*M_*64;         // 24576
  u16* woB    = wqB + 24576;                    // 8192
  u16* w1B    = woB + 8192;                     // 16384
  u16* w2B    = w1B + 16384;                    // 16384

  k_prep   <<<dim3(256), dim3(256), 0, stream>>>(Wqkv, Wo, Wf1, Wf2, wqB, woB, w1B, w2B);

  // CSR build (edge list identical for all t)
  k_zero   <<<dim3((2*M_+255)/256), dim3(256), 0, stream>>>(deg, 2*M_);
  k_hist   <<<dim3((ETOT+255)/256), dim3(256), 0, stream>>>(ei, deg);
  k_scan1  <<<dim3(125), dim3(256), 0, stream>>>(deg, offs, bsums);
  k_scan2  <<<dim3(1),   dim3(128), 0, stream>>>(bsums, boffs);
  k_scan3  <<<dim3(125), dim3(256), 0, stream>>>(offs, boffs);
  k_scatter<<<dim3((ETOT+255)/256), dim3(256), 0, stream>>>(ei, offs, cursor, csr);

  k_gat12<<<dim3(500,T_), dim3(256), 0, stream>>>(x_seq, W1, as1, ad1, b1,
                                                  W2, as2, ad2, offs, csr, h2u, asc, adc);
  k_gat2b<<<dim3(500,T_), dim3(256), 0, stream>>>(h2u, asc, adc, b2, offs, csr, seqh);

  for(int i=0;i<2;i++){
    k_layer<<<dim3(8000), dim3(192), 0, stream>>>(seqh,
        wqB + (size_t)i*12288, woB + (size_t)i*4096,
        w1B + (size_t)i*8192,  w2B + (size_t)i*8192,
        bqkv + (size_t)i*192,  bo   + (size_t)i*64,
        bf1p + (size_t)i*128,  bf2p + (size_t)i*64,
        g1   + (size_t)i*64,   be1  + (size_t)i*64,
        g2   + (size_t)i*64,   be2  + (size_t)i*64,
        i==1);
  }

  k_head<<<dim3(125), dim3(256), 0, stream>>>(seqh, Wh, bh, (float*)d_out);
}

// Round 15
// 413.561 us; speedup vs baseline: 30.2687x; 1.0853x over previous
//
#include <hip/hip_runtime.h>
#include <hip/hip_bf16.h>

#define B_ 16
#define T_ 12
#define N_ 2000
#define E_ 8000
#define M_ 32000                 // B_*N_
#define ETOT (B_*E_ + M_)        // 160000 edges incl. self loops
#define D_ 64

typedef __hip_bfloat16 bf16;
typedef unsigned short u16;
typedef __attribute__((ext_vector_type(8))) _Float16 half8;
typedef __attribute__((ext_vector_type(2))) _Float16 h2v;
typedef __attribute__((ext_vector_type(4))) float f32x4;

__device__ __forceinline__ float bfu(u16 u){ return __uint_as_float(((unsigned int)u)<<16); }
__device__ __forceinline__ u16 f2bu(float f){
  unsigned int x = __float_as_uint(f);
  x += 0x7FFFu + ((x >> 16) & 1u);
  return (u16)(x >> 16);
}
__device__ __forceinline__ u16 f2h(float f){
  _Float16 h = (_Float16)f; u16 r; __builtin_memcpy(&r, &h, 2); return r;
}
__device__ __forceinline__ float h2f(u16 u){
  _Float16 h; __builtin_memcpy(&h, &u, 2); return (float)h;
}
__device__ __forceinline__ h2v u2h(unsigned u){ h2v r; __builtin_memcpy(&r,&u,4); return r; }

// ---------------- weight prep: f16 MFMA B-fragments + PE table ----------------
// B-frag (verified R11/R12): value = W[n = nt*16+(lane&15)][k = c*32+(lane>>4)*8+j]
// wqB [L][12][2][64][8] 24576 | woB [L][4][2][64][8] 8192
// w1B [L][ 8][2][64][8] 16384 | w2B [L][4][4][64][8] 16384 | peT f32 [12][64]
__global__ void k_prep(const float* __restrict__ Wqkv, const float* __restrict__ Wo,
                       const float* __restrict__ Wf1, const float* __restrict__ Wf2,
                       u16* __restrict__ wqB, u16* __restrict__ woB,
                       u16* __restrict__ w1B, u16* __restrict__ w2B,
                       float* __restrict__ peT){
  int i = blockIdx.x*256 + threadIdx.x;    // 260 blocks
  if(i < 24576){
    int l=i/12288, r=i-l*12288;
    int nt=r>>10, r2=r&1023, c=r2>>9, r3=r2&511, lane=r3>>3, jj=r3&7;
    int m=lane&15, q=lane>>4;
    wqB[i] = f2h(Wqkv[l*12288 + (nt*16+m)*64 + c*32 + q*8 + jj]);
  } else if(i < 32768){
    int k2=i-24576;
    int l=k2>>12, r=k2&4095;
    int nt=r>>10, r2=r&1023, c=r2>>9, r3=r2&511, lane=r3>>3, jj=r3&7;
    int m=lane&15, q=lane>>4;
    woB[k2] = f2h(Wo[l*4096 + (nt*16+m)*64 + c*32 + q*8 + jj]);
  } else if(i < 49152){
    int k2=i-32768;
    int l=k2>>13, r=k2&8191;
    int nt=r>>10, r2=r&1023, c=r2>>9, r3=r2&511, lane=r3>>3, jj=r3&7;
    int m=lane&15, q=lane>>4;
    w1B[k2] = f2h(Wf1[l*8192 + (nt*16+m)*64 + c*32 + q*8 + jj]);
  } else if(i < 65536){
    int k2=i-49152;
    int l=k2>>13, r=k2&8191;
    int nt=r>>11, r2=r&2047, c=r2>>9, r3=r2&511, lane=r3>>3, jj=r3&7;
    int m=lane&15, q=lane>>4;
    w2B[k2] = f2h(Wf2[l*8192 + (nt*16+m)*128 + c*32 + q*8 + jj]);
  } else {
    int i2 = i - 65536;
    if(i2 < 768){
      int t=i2>>6, ch=i2&63;
      float ang = (float)t * __expf(-0.14391156463f * (float)(ch & ~1));
      peT[i2] = (ch&1) ? __cosf(ang) : __sinf(ang);
    }
  }
}

// ---------------- CSR build ----------------
__global__ void k_zero(int* __restrict__ p, int n){
  int i = blockIdx.x*256 + threadIdx.x; if(i<n) p[i]=0;
}

__global__ void k_hist(const int* __restrict__ ei, int* __restrict__ deg){
  int e = blockIdx.x*256 + threadIdx.x; if(e>=ETOT) return;
  int dst;
  if (e < B_*E_){ int b = e / E_; int k = e - b*E_; dst = ei[E_ + k] + b*N_; }
  else dst = e - B_*E_;
  atomicAdd(&deg[dst], 1);
}

__global__ void k_scan1(const int* __restrict__ deg, int* __restrict__ offs, int* __restrict__ bsums){
  __shared__ int s[256];
  int tid = threadIdx.x; int g = blockIdx.x*256 + tid;
  s[tid] = deg[g]; __syncthreads();
  for(int off=1; off<256; off<<=1){
    int a = (tid>=off) ? s[tid-off] : 0; __syncthreads();
    s[tid] += a; __syncthreads();
  }
  offs[g+1] = s[tid];
  if(tid==255) bsums[blockIdx.x] = s[255];
}

__global__ void k_scan2(const int* __restrict__ bsums, int* __restrict__ boffs){
  __shared__ int s[128];
  int tid = threadIdx.x;
  int v = (tid<125) ? bsums[tid] : 0;
  s[tid] = v; __syncthreads();
  for(int off=1; off<128; off<<=1){
    int a = (tid>=off) ? s[tid-off] : 0; __syncthreads();
    s[tid] += a; __syncthreads();
  }
  if(tid<125) boffs[tid] = s[tid] - v;
}

__global__ void k_scan3(int* __restrict__ offs, const int* __restrict__ boffs){
  int tid = threadIdx.x; int g = blockIdx.x*256 + tid;
  offs[g+1] += boffs[blockIdx.x];
  if(g==0) offs[0]=0;
}

__global__ void k_scatter(const int* __restrict__ ei, const int* __restrict__ offs,
                          int* __restrict__ cursor, int* __restrict__ csr){
  int e = blockIdx.x*256 + threadIdx.x; if(e>=ETOT) return;
  int src, dst;
  if (e < B_*E_){ int b=e/E_; int k=e-b*E_; src=ei[k]+b*N_; dst=ei[E_+k]+b*N_; }
  else { src = e - B_*E_; dst = src; }
  int pos = atomicAdd(&cursor[dst], 1);
  csr[offs[dst]+pos] = src;
}

// ---------------- fused GAT1 + GAT2 feature/score ----------------
// Thread = (node m, head h). Edge loop runs ONLY head h (was 4x redundant across
// the lane-quad in R14); A[0..3] rebuilt via 3 intra-quad shuffles for the matmul.
__global__ __launch_bounds__(256) void k_gat12(
  const float* __restrict__ x_seq, const float* __restrict__ W1,
  const float* __restrict__ as1, const float* __restrict__ ad1, const float* __restrict__ b1,
  const float* __restrict__ W2, const float* __restrict__ as2, const float* __restrict__ ad2,
  const int* __restrict__ offs, const int* __restrict__ csr,
  u16* __restrict__ h2u, float* __restrict__ asc, float* __restrict__ adc)
{
  __shared__ float W2s[2048];       // [k=32][c=64] fp32
  __shared__ float a2s[64], a2d[64];
  int tid = threadIdx.x;
  for(int i=tid;i<2048;i+=256) W2s[i]=W2[i];
  if(tid<64){ a2s[tid]=as2[tid]; a2d[tid]=ad2[tid]; }
  __syncthreads();

  int t = blockIdx.y;
  int id = blockIdx.x*256 + tid;     // 500*256 = M_*4
  int m = id>>2, h = id&3;

  float sS=0.f, sD=0.f;
  #pragma unroll
  for(int c=0;c<8;c++){ float w=W1[h*8+c]; sS+=w*as1[h*8+c]; sD+=w*ad1[h*8+c]; }
  unsigned um=(unsigned)m, b=um/N_, n=um-b*N_;
  const float* xsl = x_seq + (size_t)(b*T_+t)*N_;
  float xm = xsl[n];
  int e0=offs[m], e1=offs[m+1];
  // single-pass softmax, one head per thread
  float sum=0.f, ax=0.f;
  for(int e=e0;e<e1;e++){
    unsigned s=(unsigned)csr[e]; unsigned sn=s - (s/N_)*N_;
    float xv = xsl[sn];
    float ee = xv*sS + xm*sD; ee = ee>0.f ? ee : 0.2f*ee;
    float w = __expf(ee); sum+=w; ax+=w*xv;
  }
  float Ah = ax/(sum+1e-16f);
  // rebuild A[0..3] across the lane-quad
  float a1=__shfl_xor(Ah,1), a2v=__shfl_xor(Ah,2), a3=__shfl_xor(a1,2);
  float A[4];
  A[h]=Ah; A[h^1]=a1; A[h^2]=a2v; A[h^3]=a3;

  float acc[16];
  #pragma unroll
  for(int c=0;c<16;c++) acc[c]=0.f;
  #pragma unroll
  for(int k=0;k<32;k++){
    int hs = k>>3;
    float v = A[hs]*W1[k] + b1[k]; v = v>0.f ? v : 0.f;   // relu(out1)
    #pragma unroll
    for(int c=0;c<16;c++) acc[c] += v*W2s[k*64 + h*16 + c];
  }
  // pack bf16, 4x uint2 stores
  uint2* hp = (uint2*)(h2u + ((size_t)t*M_ + m)*64 + h*16);
  #pragma unroll
  for(int c2=0;c2<4;c2++){
    uint2 p;
    p.x = (unsigned)f2bu(acc[4*c2+0]) | ((unsigned)f2bu(acc[4*c2+1])<<16);
    p.y = (unsigned)f2bu(acc[4*c2+2]) | ((unsigned)f2bu(acc[4*c2+3])<<16);
    hp[c2] = p;
  }
  float ss=0.f, sd=0.f;
  #pragma unroll
  for(int c=0;c<16;c++){ ss += acc[c]*a2s[h*16+c]; sd += acc[c]*a2d[h*16+c]; }
  asc[((size_t)t*M_+m)*4+h]=ss; adc[((size_t)t*M_+m)*4+h]=sd;
}

// ---------------- GAT2 softmax-aggregate + bias + relu + PE(table); f16 out ------
__global__ __launch_bounds__(256) void k_gat2b(
  const u16* __restrict__ h2u, const float* __restrict__ asc, const float* __restrict__ adc,
  const float* __restrict__ b2, const int* __restrict__ offs, const int* __restrict__ csr,
  const float* __restrict__ peT, u16* __restrict__ seq)
{
  int t = blockIdx.y;
  int id = blockIdx.x*256 + threadIdx.x;
  int m = id>>2, h = id&3;
  float am = adc[((size_t)t*M_+m)*4+h];
  int e0=offs[m], e1=offs[m+1];
  float sum=0.f;
  float A[16];
  #pragma unroll
  for(int c=0;c<16;c++) A[c]=0.f;
  for(int e=e0;e<e1;e++){
    int s=csr[e];
    float ee = asc[((size_t)t*M_+s)*4+h] + am; ee = ee>0.f ? ee : 0.2f*ee;
    float w = __expf(ee); sum += w;
    const uint2* hp = (const uint2*)(h2u + ((size_t)t*M_ + s)*64 + h*16);
    #pragma unroll
    for(int c2=0;c2<4;c2++){
      uint2 p = hp[c2];
      A[4*c2+0] += w*bfu((u16)(p.x));
      A[4*c2+1] += w*bfu((u16)(p.x>>16));
      A[4*c2+2] += w*bfu((u16)(p.y));
      A[4*c2+3] += w*bfu((u16)(p.y>>16));
    }
  }
  float inv = 1.f/(sum + 1e-16f);
  #pragma unroll
  for(int c=0;c<16;c++){
    int ch = h*16 + c;
    float v = A[c]*inv + b2[ch]; v = v>0.f ? v : 0.f;
    seq[((size_t)t*M_ + m)*64 + ch] = f2h(v + peT[t*64+ch]);
  }
}

// ---------------- fused transformer layer: all-f16 dataflow, packed attention ----
__global__ __launch_bounds__(192) void k_layer(
  u16* __restrict__ seq,
  const u16* __restrict__ wqB, const u16* __restrict__ woB,
  const u16* __restrict__ w1B, const u16* __restrict__ w2B,
  const float* __restrict__ bqkv, const float* __restrict__ bo,
  const float* __restrict__ bf1,  const float* __restrict__ bf2,
  const float* __restrict__ g1,   const float* __restrict__ be1,
  const float* __restrict__ g2,   const float* __restrict__ be2,
  int last)
{
  __shared__ __align__(16) u16 QKV[10368];   // 3*48*72 u16 = 20736 B
  u16* Hd = QKV + 3456;                      // H[48][136] overlays K,V
  int tid=threadIdx.x, w=tid>>6, lane=tid&63;
  int m=lane&15, q=lane>>4;
  int r = w*16 + m;
  int nr = r/12, tr = r - nr*12;
  int node_r = blockIdx.x*4 + nr;

  int trr[4]; size_t base_rr[4];
  #pragma unroll
  for(int rg=0;rg<4;rg++){
    int rc = w*16 + q*4 + rg;
    int nn = rc/12; trr[rg] = rc - nn*12;
    base_rr[rg] = ((size_t)trr[rg]*M_ + (size_t)blockIdx.x*4 + nn)*64;
  }

  // ---- QKV projection: direct half8 A-frags from f16 global ----
  const u16* xrow = seq + ((size_t)tr*M_ + node_r)*64;
  half8 xa0 = *(const half8*)(xrow + q*8);
  half8 xa1 = *(const half8*)(xrow + 32 + q*8);
  const half8* wqv = (const half8*)wqB;
  #pragma unroll
  for(int nt=0; nt<12; nt++){
    f32x4 acc={0.f,0.f,0.f,0.f};
    acc = __builtin_amdgcn_mfma_f32_16x16x32_f16(xa0, wqv[(nt*2+0)*64+lane], acc,0,0,0);
    acc = __builtin_amdgcn_mfma_f32_16x16x32_f16(xa1, wqv[(nt*2+1)*64+lane], acc,0,0,0);
    int cg = nt*16+m; float bias = bqkv[cg];
    int s = nt>>2, lc = cg&63;
    #pragma unroll
    for(int rg=0;rg<4;rg++){
      int row = w*16 + q*4 + rg;
      QKV[s*3456 + row*72 + lc] = f2h(acc[rg]+bias);
    }
  }
  __syncthreads();

  // ---- attention: 192 lanes = (node an, head ah, time at); fdot2 + pk_fma ----
  {
    int an = tid/48, rem = tid - an*48;
    int ah = rem/12, at = rem - ah*12;
    u16* qrow = &QKV[(an*12+at)*72 + ah*16];
    uint4 qa = ((const uint4*)qrow)[0], qb = ((const uint4*)qrow)[1];
    float s[12];
    #pragma unroll
    for(int t2=0;t2<12;t2++){
      const uint4* kp = (const uint4*)&QKV[3456 + (an*12+t2)*72 + ah*16];
      uint4 ka=kp[0], kb=kp[1];
      float d=0.f;
      d=__builtin_amdgcn_fdot2(u2h(qa.x),u2h(ka.x),d,false);
      d=__builtin_amdgcn_fdot2(u2h(qa.y),u2h(ka.y),d,false);
      d=__builtin_amdgcn_fdot2(u2h(qa.z),u2h(ka.z),d,false);
      d=__builtin_amdgcn_fdot2(u2h(qa.w),u2h(ka.w),d,false);
      d=__builtin_amdgcn_fdot2(u2h(qb.x),u2h(kb.x),d,false);
      d=__builtin_amdgcn_fdot2(u2h(qb.y),u2h(kb.y),d,false);
      d=__builtin_amdgcn_fdot2(u2h(qb.z),u2h(kb.z),d,false);
      d=__builtin_amdgcn_fdot2(u2h(qb.w),u2h(kb.w),d,false);
      s[t2] = d*0.25f;                 // 1/sqrt(16)
    }
    float mx=s[0];
    #pragma unroll
    for(int t2=1;t2<12;t2++) mx=fmaxf(mx,s[t2]);
    float sum=0.f;
    #pragma unroll
    for(int t2=0;t2<12;t2++){ s[t2]=__expf(s[t2]-mx); sum+=s[t2]; }
    float inv=1.f/sum;
    half8 o0, o1;
    #pragma unroll
    for(int i=0;i<8;i++){ o0[i]=(_Float16)0.f; o1[i]=(_Float16)0.f; }
    #pragma unroll
    for(int t2=0;t2<12;t2++){
      const half8* vr = (const half8*)&QKV[6912 + (an*12+t2)*72 + ah*16];
      _Float16 wh = (_Float16)s[t2];
      o0 += vr[0]*wh; o1 += vr[1]*wh;       // v_pk_fma_f16
    }
    _Float16 ih = (_Float16)inv;
    ((half8*)qrow)[0]=o0*ih; ((half8*)qrow)[1]=o1*ih;
  }
  __syncthreads();

  // ---- Wo + residual + LN1 (O in Q region; direct half8 A-frags) ----
  half8 oa0 = *(const half8*)&QKV[r*72 + q*8];
  half8 oa1 = *(const half8*)&QKV[r*72 + 32 + q*8];
  const half8* wov=(const half8*)woB;
  float y[4][4];
  #pragma unroll
  for(int nt=0;nt<4;nt++){
    f32x4 acc={0.f,0.f,0.f,0.f};
    acc = __builtin_amdgcn_mfma_f32_16x16x32_f16(oa0, wov[(nt*2+0)*64+lane], acc,0,0,0);
    acc = __builtin_amdgcn_mfma_f32_16x16x32_f16(oa1, wov[(nt*2+1)*64+lane], acc,0,0,0);
    int col=nt*16+m; float bias=bo[col];
    #pragma unroll
    for(int rg=0;rg<4;rg++)
      y[nt][rg] = acc[rg] + bias + h2f(seq[base_rr[rg] + col]);
  }
  float mu[4], rs[4];
  #pragma unroll
  for(int rg=0;rg<4;rg++){
    float sm=(y[0][rg]+y[1][rg])+(y[2][rg]+y[3][rg]);
    sm+=__shfl_xor(sm,1); sm+=__shfl_xor(sm,2); sm+=__shfl_xor(sm,4); sm+=__shfl_xor(sm,8);
    mu[rg]=sm*(1.f/64.f);
    float d0=y[0][rg]-mu[rg],d1=y[1][rg]-mu[rg],d2=y[2][rg]-mu[rg],d3=y[3][rg]-mu[rg];
    float vv=(d0*d0+d1*d1)+(d2*d2+d3*d3);
    vv+=__shfl_xor(vv,1); vv+=__shfl_xor(vv,2); vv+=__shfl_xor(vv,4); vv+=__shfl_xor(vv,8);
    rs[rg]=rsqrtf(vv*(1.f/64.f)+1e-5f);
  }
  #pragma unroll
  for(int nt=0;nt<4;nt++){
    int col=nt*16+m; float g=g1[col], be=be1[col];
    #pragma unroll
    for(int rg=0;rg<4;rg++){
      float v=(y[nt][rg]-mu[rg])*rs[rg]*g+be;
      y[nt][rg]=v;                                  // FF residual (f32)
      QKV[(w*16+q*4+rg)*72 + col]=f2h(v);           // y -> wave-own rows (f16)
    }
  }

  // ---- FF1: y A-frags (wave-own, direct half8); H -> pitch-136 overlay ----
  half8 ya0 = *(const half8*)&QKV[r*72 + q*8];
  half8 ya1 = *(const half8*)&QKV[r*72 + 32 + q*8];
  const half8* w1v=(const half8*)w1B;
  #pragma unroll
  for(int nt=0;nt<8;nt++){
    f32x4 acc={0.f,0.f,0.f,0.f};
    acc = __builtin_amdgcn_mfma_f32_16x16x32_f16(ya0, w1v[(nt*2+0)*64+lane], acc,0,0,0);
    acc = __builtin_amdgcn_mfma_f32_16x16x32_f16(ya1, w1v[(nt*2+1)*64+lane], acc,0,0,0);
    float bias=bf1[nt*16+m];
    #pragma unroll
    for(int rg=0;rg<4;rg++)
      Hd[(w*16+q*4+rg)*136 + nt*16+m] = f2h(fmaxf(acc[rg]+bias, 0.f));
  }

  // ---- FF2: H A-frags direct half8 + residual y + LN2 + store f16 ----
  half8 ha[4];
  #pragma unroll
  for(int c=0;c<4;c++)
    ha[c] = *(const half8*)&Hd[r*136 + c*32 + q*8];
  const half8* w2v=(const half8*)w2B;
  #pragma unroll
  for(int nt=0;nt<4;nt++){
    f32x4 acc={0.f,0.f,0.f,0.f};
    #pragma unroll
    for(int c=0;c<4;c++)
      acc = __builtin_amdgcn_mfma_f32_16x16x32_f16(ha[c], w2v[(nt*4+c)*64+lane], acc,0,0,0);
    int col=nt*16+m; float bias=bf2[col];
    #pragma unroll
    for(int rg=0;rg<4;rg++)
      y[nt][rg] = acc[rg] + bias + y[nt][rg];
  }
  #pragma unroll
  for(int rg=0;rg<4;rg++){
    float sm=(y[0][rg]+y[1][rg])+(y[2][rg]+y[3][rg]);
    sm+=__shfl_xor(sm,1); sm+=__shfl_xor(sm,2); sm+=__shfl_xor(sm,4); sm+=__shfl_xor(sm,8);
    mu[rg]=sm*(1.f/64.f);
    float d0=y[0][rg]-mu[rg],d1=y[1][rg]-mu[rg],d2=y[2][rg]-mu[rg],d3=y[3][rg]-mu[rg];
    float vv=(d0*d0+d1*d1)+(d2*d2+d3*d3);
    vv+=__shfl_xor(vv,1); vv+=__shfl_xor(vv,2); vv+=__shfl_xor(vv,4); vv+=__shfl_xor(vv,8);
    rs[rg]=rsqrtf(vv*(1.f/64.f)+1e-5f);
  }
  #pragma unroll
  for(int nt=0;nt<4;nt++){
    int col=nt*16+m; float g=g2[col], be=be2[col];
    #pragma unroll
    for(int rg=0;rg<4;rg++){
      if(!last || trr[rg]==11)
        seq[base_rr[rg] + col] = f2h((y[nt][rg]-mu[rg])*rs[rg]*g + be);
    }
  }
}

// ---------------- prediction head (f16 seq in) ----------------
__global__ void k_head(const u16* __restrict__ seq, const float* __restrict__ Wh,
                       const float* __restrict__ bh, float* __restrict__ out){
  int m = blockIdx.x*256 + threadIdx.x; if(m>=M_) return;
  const u16* row = seq + ((size_t)11*M_ + m)*64;
  float a0=bh[0], a1=bh[1], a2=bh[2];
  #pragma unroll
  for(int d=0;d<64;d++){
    float x = h2f(row[d]);
    a0 += x*Wh[d]; a1 += x*Wh[64+d]; a2 += x*Wh[128+d];
  }
  unsigned b=(unsigned)m/N_, n=(unsigned)m-b*N_;
  out[(b*3+0)*N_+n] = a0;
  out[(b*3+1)*N_+n] = a1;
  out[(b*3+2)*N_+n] = a2;
}

extern "C" void kernel_launch(void* const* d_in, const int* in_sizes, int n_in,
                              void* d_out, int out_size, void* d_ws, size_t ws_size,
                              hipStream_t stream)
{
  const float* x_seq=(const float*)d_in[0];
  const int*   ei   =(const int*)d_in[1];
  const float* W1   =(const float*)d_in[2];
  const float* as1  =(const float*)d_in[3];
  const float* ad1  =(const float*)d_in[4];
  const float* b1   =(const float*)d_in[5];
  const float* W2   =(const float*)d_in[6];
  const float* as2  =(const float*)d_in[7];
  const float* ad2  =(const float*)d_in[8];
  const float* b2   =(const float*)d_in[9];
  const float* Wqkv =(const float*)d_in[10];
  const float* bqkv =(const float*)d_in[11];
  const float* Wo   =(const float*)d_in[12];
  const float* bo   =(const float*)d_in[13];
  const float* Wf1  =(const float*)d_in[14];
  const float* bf1p =(const float*)d_in[15];
  const float* Wf2  =(const float*)d_in[16];
  const float* bf2p =(const float*)d_in[17];
  const float* g1   =(const float*)d_in[18];
  const float* be1  =(const float*)d_in[19];
  const float* g2   =(const float*)d_in[20];
  const float* be2  =(const float*)d_in[21];
  const float* Wh   =(const float*)d_in[22];
  const float* bh   =(const float*)d_in[23];

  // workspace layout (~112 MB)
  u16* seqh   = (u16*)d_ws;                     // [T][M][64] f16  24,576,000 u16
  float* asc  = (float*)(seqh + 24576000);      // [T][M][4]        1,536,000 f
  float* adc  = asc + 1536000;                  //                  1,536,000 f
  int* deg    = (int*)(adc + 1536000);
  int* cursor = deg + M_;
  int* offs   = cursor + M_;                    // M_+1 used
  int* bsums  = offs + (M_ + 2);
  int* boffs  = bsums + 128;
  int* csr    = boffs + 128;                    // ETOT
  u16* h2u    = (u16*)(csr + ETOT);             // [T][M][64]   24,576,000 u16
  u16* wqB    = h2u + (size_t)T_*M_*64;         // 24576
  u16* woB    = wqB + 24576;                    // 8192
  u16* w1B    = woB + 8192;                     // 16384
  u16* w2B    = w1B + 16384;                    // 16384
  float* peT  = (float*)(w2B + 16384);          // 768

  k_prep   <<<dim3(260), dim3(256), 0, stream>>>(Wqkv, Wo, Wf1, Wf2, wqB, woB, w1B, w2B, peT);

  // CSR build (edge list identical for all t)
  k_zero   <<<dim3((2*M_+255)/256), dim3(256), 0, stream>>>(deg, 2*M_);
  k_hist   <<<dim3((ETOT+255)/256), dim3(256), 0, stream>>>(ei, deg);
  k_scan1  <<<dim3(125), dim3(256), 0, stream>>>(deg, offs, bsums);
  k_scan2  <<<dim3(1),   dim3(128), 0, stream>>>(bsums, boffs);
  k_scan3  <<<dim3(125), dim3(256), 0, stream>>>(offs, boffs);
  k_scatter<<<dim3((ETOT+255)/256), dim3(256), 0, stream>>>(ei, offs, cursor, csr);

  k_gat12<<<dim3(500,T_), dim3(256), 0, stream>>>(x_seq, W1, as1, ad1, b1,
                                                  W2, as2, ad2, offs, csr, h2u, asc, adc);
  k_gat2b<<<dim3(500,T_), dim3(256), 0, stream>>>(h2u, asc, adc, b2, offs, csr, peT, seqh);

  for(int i=0;i<2;i++){
    k_layer<<<dim3(8000), dim3(192), 0, stream>>>(seqh,
        wqB + (size_t)i*12288, woB + (size_t)i*4096,
        w1B + (size_t)i*8192,  w2B + (size_t)i*8192,
        bqkv + (size_t)i*192,  bo   + (size_t)i*64,
        bf1p + (size_t)i*128,  bf2p + (size_t)i*64,
        g1   + (size_t)i*64,   be1  + (size_t)i*64,
        g2   + (size_t)i*64,   be2  + (size_t)i*64,
        i==1);
  }

  k_head<<<dim3(125), dim3(256), 0, stream>>>(seqh, Wh, bh, (float*)d_out);
}